// Round 8
// baseline (657.267 us; speedup 1.0000x reference)
//
#include <hip/hip_runtime.h>
#include <cstdint>

typedef unsigned short u16;
typedef unsigned int   u32;

typedef __attribute__((ext_vector_type(8))) short bf16x8;
typedef __attribute__((ext_vector_type(4))) float f32x4;

#define DEV __device__ __forceinline__

static constexpr int HP = 66, WP = 66;   // padded spatial

DEV u16 f2bf(float f) {
  u32 u = __float_as_uint(f);
  u32 r = (u + 0x7fffu + ((u >> 16) & 1u)) >> 16;
  return (u16)r;
}
DEV float bf2f(u16 v) { return __uint_as_float((u32)v << 16); }

DEV void gload_lds16(const void* g, void* s) {
  __builtin_amdgcn_global_load_lds(
      (const __attribute__((address_space(1))) void*)g,
      (__attribute__((address_space(3))) void*)s, 16, 0, 0);
}

// ---------------- weight repack: OIHW fp32 -> [co][(ky*3+kx)*Cin+ci] bf16 ----------
__global__ __launch_bounds__(256) void repack_w_kernel(const float* __restrict__ src,
                                                       u16* __restrict__ dst,
                                                       int Cin, int K, int total,
                                                       int ksq, int kdim) {
  for (int idx = blockIdx.x * 256 + threadIdx.x; idx < total; idx += gridDim.x * 256) {
    int co = idx / K;
    int r  = idx - co * K;
    int s  = r / Cin;
    int ci = r - s * Cin;
    int ky = s / kdim, kx = s - ky * kdim;
    dst[idx] = f2bf(src[(co * Cin + ci) * ksq + ky * kdim + kx]);
  }
}

// ---------------- SS_T[i][o] = sum_{kh,kw} mod_w[o][i]^2 ----------------
__global__ __launch_bounds__(256) void modw_ss_kernel(const float* __restrict__ w,
                                                      float* __restrict__ SS_T) {
  int o = blockIdx.x, i = threadIdx.x;
  const float* p = w + (size_t)(o * 256 + i) * 9;
  float s = 0.f;
#pragma unroll
  for (int k = 0; k < 9; ++k) s += p[k] * p[k];
  SS_T[i * 256 + o] = s;
}

// ---------------- mvec[b][i] = style . style_w[i] + style_b[i] + 1 ----------------
__global__ __launch_bounds__(256) void style_mvec_kernel(const float* __restrict__ style,
                                                         const float* __restrict__ style_w,
                                                         const float* __restrict__ style_b,
                                                         float* __restrict__ mvec) {
  __shared__ float st[512];
  int b = blockIdx.x, t = threadIdx.x;
  for (int k = t; k < 512; k += 256) st[k] = style[b * 512 + k];
  __syncthreads();
  const float4* wr = (const float4*)(style_w + t * 512);
  float acc = 0.f;
  for (int k = 0; k < 128; ++k) {
    float4 w4 = wr[k];
    acc += w4.x * st[k*4] + w4.y * st[k*4+1] + w4.z * st[k*4+2] + w4.w * st[k*4+3];
  }
  mvec[b * 256 + t] = acc + style_b[t] + 1.f;
}

// ---------------- dvec[b][o] = rsqrt(sum_i mvec[b][i]^2 * SS_T[i][o] + eps) ---------
__global__ __launch_bounds__(256) void demod_kernel(const float* __restrict__ mvec,
                                                    const float* __restrict__ SS_T,
                                                    float* __restrict__ dvec) {
  __shared__ float m2[256];
  int b = blockIdx.x, t = threadIdx.x;
  float mv = mvec[b * 256 + t];
  m2[t] = mv * mv;
  __syncthreads();
  float acc = 0.f;
  for (int i = 0; i < 256; ++i) acc += m2[i] * SS_T[i * 256 + t];
  dvec[b * 256 + t] = rsqrtf(acc + 1e-8f);
}

// ---------------- scTb[b][co][ci] = sc_w[co][ci] / dvec[b][co]  (bf16) --------------
__global__ __launch_bounds__(256) void scale_sc_kernel(const float* __restrict__ sc_w,
                                                       const float* __restrict__ dvec,
                                                       u16* __restrict__ scTb) {
  int idx = blockIdx.x * 256 + threadIdx.x;   // 32*256*128 total
  int ci = idx & 127;
  int co = (idx >> 7) & 255;
  int b  = idx >> 15;
  scTb[idx] = f2bf(sc_w[co * 128 + ci] / dvec[b * 256 + co]);
}

// ---------------- tb2[b][co] = swish(temb[b]) . temb_w[co] + temb_b + conv1_b -------
__global__ __launch_bounds__(256) void temb_proj_kernel(const float* __restrict__ temb,
                                                        const float* __restrict__ temb_w,
                                                        const float* __restrict__ temb_b,
                                                        const float* __restrict__ conv1_b,
                                                        float* __restrict__ tb2) {
  __shared__ float sw[512];
  int b = blockIdx.x, t = threadIdx.x;
  for (int k = t; k < 512; k += 256) {
    float v = temb[b * 512 + k];
    sw[k] = v / (1.f + __expf(-v));
  }
  __syncthreads();
  const float4* wr = (const float4*)(temb_w + t * 512);
  float acc = 0.f;
  for (int k = 0; k < 128; ++k) {
    float4 w4 = wr[k];
    acc += w4.x * sw[k*4] + w4.y * sw[k*4+1] + w4.z * sw[k*4+2] + w4.w * sw[k*4+3];
  }
  tb2[b * 256 + t] = acc + temb_b[t] + conv1_b[t];
}

// ---------------- halo zero: clear only border pixels of padded NHWC buffer ---------
template <int C>
__global__ __launch_bounds__(256) void halo_zero_kernel(u16* __restrict__ buf) {
  int idx = blockIdx.x * 256 + threadIdx.x;
  const int GR = C / 8;
  if (idx >= 32 * 260 * GR) return;
  int g = idx % GR;
  int p = (idx / GR) % 260;
  int b = idx / (GR * 260);
  int y, x;
  if (p < 66)       { y = 0;        x = p; }
  else if (p < 132) { y = 65;       x = p - 66; }
  else if (p < 196) { y = p - 131;  x = 0; }
  else              { y = p - 195;  x = 65; }
  uint4 z; z.x = 0; z.y = 0; z.z = 0; z.w = 0;
  *(uint4*)(buf + (((size_t)b * HP + y) * WP + x) * C + g * 8) = z;
}

// ---------------- GN1 stats ----------------
__global__ __launch_bounds__(256) void gn1_stats_kernel(const float* __restrict__ x,
                                                        float2* __restrict__ st1) {
  int bg = blockIdx.x;
  const float4* p = (const float4*)(x + (size_t)bg * 16384);
  float s = 0.f, s2 = 0.f;
  for (int i = threadIdx.x; i < 4096; i += 256) {
    float4 v = p[i];
    s  += v.x + v.y + v.z + v.w;
    s2 += v.x*v.x + v.y*v.y + v.z*v.z + v.w*v.w;
  }
  for (int d = 32; d; d >>= 1) { s += __shfl_down(s, d); s2 += __shfl_down(s2, d); }
  __shared__ float red[2][4];
  if ((threadIdx.x & 63) == 0) { red[0][threadIdx.x >> 6] = s; red[1][threadIdx.x >> 6] = s2; }
  __syncthreads();
  if (threadIdx.x == 0) {
    s  = red[0][0] + red[0][1] + red[0][2] + red[0][3];
    s2 = red[1][0] + red[1][1] + red[1][2] + red[1][3];
    float mean = s / 16384.f;
    float var  = s2 / 16384.f - mean * mean;
    st1[bg] = make_float2(mean, rsqrtf(var + 1e-5f));
  }
}

// ---------------- GN1 apply + swish -> act1p (padded NHWC bf16); also x -> xh NHWC --
__global__ __launch_bounds__(256) void gn1_apply_kernel(const float* __restrict__ x,
                                                        const float2* __restrict__ st1,
                                                        const float* __restrict__ g1,
                                                        const float* __restrict__ b1,
                                                        u16* __restrict__ act1p,
                                                        u16* __restrict__ xh) {
  __shared__ float xs[128][65];
  int blk = blockIdx.x;
  int b = blk >> 6, y = blk & 63;
  int t = threadIdx.x;
#pragma unroll 8
  for (int pass = 0; pass < 32; ++pass) {
    int c = pass * 4 + (t >> 6);
    xs[c][t & 63] = x[(((size_t)b * 128 + c) * 64 + y) * 64 + (t & 63)];
  }
  __syncthreads();
  for (int pass = 0; pass < 32; ++pass) {
    int xc = pass * 2 + (t >> 7);
    int c  = t & 127;
    float v = xs[c][xc];
    float2 ms = st1[b * 32 + (c >> 2)];
    float vn = (v - ms.x) * ms.y * g1[c] + b1[c];
    float sw = vn / (1.f + __expf(-vn));
    act1p[(((size_t)b * HP + (y + 1)) * WP + (xc + 1)) * 128 + c] = f2bf(sw);
    xh[(((size_t)b * 64 + y) * 64 + xc) * 128 + c] = f2bf(v);
  }
}

// ---------------- GN2 final: fused totals -> mean/rsqrt ----------------
__global__ void gn2_final_kernel(const float* __restrict__ st2sum, float2* __restrict__ st2) {
  int idx = blockIdx.x * 256 + threadIdx.x;
  if (idx >= 1024) return;
  float s  = st2sum[idx * 2];
  float s2 = st2sum[idx * 2 + 1];
  float mean = s / 32768.f;
  float var  = s2 / 32768.f - mean * mean;
  st2[idx] = make_float2(mean, rsqrtf(var + 1e-5f));
}

// ------- GN2 apply + swish + input-channel modulation: h1 -> act2p (padded NHWC) ----
__global__ __launch_bounds__(256) void gn2_apply_kernel(const u16* __restrict__ h1,
                                                        const float2* __restrict__ st2,
                                                        const float* __restrict__ g2,
                                                        const float* __restrict__ b2,
                                                        const float* __restrict__ mvec,
                                                        u16* __restrict__ act2p) {
  int idx = blockIdx.x * 256 + threadIdx.x;  // granule id
  int gpix = idx >> 5;
  int gi = idx & 31;
  int c0 = gi * 8;
  int b = gpix >> 12, y = (gpix >> 6) & 63, x = gpix & 63;
  uint4 raw = *(const uint4*)(h1 + (size_t)gpix * 256 + c0);
  const u16* rs = (const u16*)&raw;
  float2 ms = st2[b * 32 + gi];
  const float* mv = mvec + b * 256 + c0;
  u16 outp[8];
#pragma unroll
  for (int e = 0; e < 8; ++e) {
    float v  = bf2f(rs[e]);
    float vn = (v - ms.x) * ms.y * g2[c0 + e] + b2[c0 + e];
    float sw = vn / (1.f + __expf(-vn));
    outp[e] = f2bf(sw * mv[e]);
  }
  *(uint4*)(act2p + (((size_t)b * HP + (y + 1)) * WP + (x + 1)) * 256 + c0) = *(const uint4*)outp;
}

// ---- implicit-GEMM conv: 256x256 tile, 16 waves (4x4), BK=64, 2 phases by k-half ---
// LDS: per buffer, A = two 16KB k-half sub-tiles (256 rows x 32 cols, 64B rows,
// swizzle gr^=(row&3)), B likewise; dbuf = 128 KB. Phase = { vmcnt(2); barrier;
// stage k-half of kt+1 into other buf; 8 ds_read; lgkmcnt(0); 16 MFMA }.
// Each ds_read_b128 covers a contiguous 1024B block -> conflict-free.
// MODE 0: conv1 -> h1 bf16 NHWC + fused GN2 partial stats.
// MODE 2: modconv + fused 1x1 shortcut -> d_out NCHW fp32.
template <int MODE>
__global__ __launch_bounds__(1024, 4) void igemm_kernel(const u16* __restrict__ act,
                                                        const u16* __restrict__ wT,
                                                        const float* __restrict__ epi,
                                                        const u16* __restrict__ xh,
                                                        const u16* __restrict__ scTb,
                                                        const float* __restrict__ sc_b,
                                                        u16* __restrict__ h1out,
                                                        float* __restrict__ fout,
                                                        float* __restrict__ st2sum) {
  constexpr int CIN    = (MODE == 0) ? 128 : 256;
  constexpr int NSUB   = CIN / 64;
  constexpr int KW     = CIN * 9;
  constexpr int NKMAIN = KW / 64;                 // 18 / 36
  constexpr int NKT    = (MODE == 2) ? NKMAIN + 2 : NKMAIN;

  __shared__ __align__(16) unsigned char lds[131072];
  const int tid  = threadIdx.x;
  const int wave = tid >> 6, lane = tid & 63;
  const int wm = wave >> 2, wn = wave & 3;        // 4 x 4 waves
  const int m_base = blockIdx.x * 256;
  const int bimg = m_base >> 12;
  const int ln = lane & 15, l4 = lane >> 4;

  // staging lane constants: wave stages rows [wave*16, +16) of each sub-tile
  const int srow = lane >> 2;                     // 0..15 (row within wave's chunk)
  const int glog = (lane & 3) ^ (srow & 3);       // pre-swizzled source granule (col)

  u32 pixA, pixX = 0, rowB, rowS = 0;
  {
    int r = wave * 16 + srow;                     // 0..255
    int m = m_base + r;
    int y = (m >> 6) & 63, x = m & 63;
    pixA = (u32)((bimg * HP + y) * WP + x) * CIN + glog * 8;
    if (MODE == 2) pixX = (u32)m * 128 + glog * 8;
    rowB = (u32)r * KW + glog * 8;
    if (MODE == 2) rowS = (u32)(bimg * 256 + r) * 128 + glog * 8;
  }

  f32x4 acc[4][4];
#pragma unroll
  for (int i = 0; i < 4; ++i)
#pragma unroll
    for (int j = 0; j < 4; ++j) acc[i][j] = (f32x4){0.f, 0.f, 0.f, 0.f};

  // stage k-half h of tile kt into buffer buf (1 A-load + 1 B-load per thread)
  auto stage = [&](int kt, int h, int buf) {
    unsigned char* dstA = lds + buf * 65536 + h * 16384 + wave * 1024;
    unsigned char* dstB = dstA + 32768;
    if (MODE == 2 && kt >= NKMAIN) {
      u32 ko = (u32)(kt - NKMAIN) * 64 + h * 32;
      gload_lds16(xh   + pixX + ko, dstA);
      gload_lds16(scTb + rowS + ko, dstB);
    } else {
      int tap = kt / NSUB;
      int kin = (kt - tap * NSUB) * 64 + h * 32;
      int ky = tap / 3, kx = tap - ky * 3;
      u32 koA = (u32)((ky * WP + kx) * CIN + kin);
      gload_lds16(act + pixA + koA, dstA);
      gload_lds16(wT  + rowB + (u32)(kt * 64 + h * 32), dstB);
    }
  };

  bf16x8 af[4], bf[4];
  auto ldA = [&](int kk, int buf) {
    const unsigned char* As = lds + buf * 65536 + kk * 16384;
#pragma unroll
    for (int f = 0; f < 4; ++f) {
      int row = wm * 64 + f * 16 + ln;
      int gr  = l4 ^ (ln & 3);
      af[f] = *(const bf16x8*)(As + row * 64 + gr * 16);
    }
  };
  auto ldB = [&](int kk, int buf) {
    const unsigned char* Bs = lds + buf * 65536 + 32768 + kk * 16384;
#pragma unroll
    for (int f = 0; f < 4; ++f) {
      int row = wn * 64 + f * 16 + ln;
      int gr  = l4 ^ (ln & 3);
      bf[f] = *(const bf16x8*)(Bs + row * 64 + gr * 16);
    }
  };
  auto mmac = [&]() {
    __builtin_amdgcn_s_setprio(1);
#pragma unroll
    for (int f = 0; f < 4; ++f)
#pragma unroll
      for (int f1 = 0; f1 < 4; ++f1)
        acc[f][f1] = __builtin_amdgcn_mfma_f32_16x16x32_bf16(af[f], bf[f1],
                                                             acc[f][f1], 0, 0, 0);
    __builtin_amdgcn_s_setprio(0);
  };

#define SB() __builtin_amdgcn_sched_barrier(0)
#define LGKM0() asm volatile("s_waitcnt lgkmcnt(0)" ::: "memory")

  // prologue: both k-halves of tile 0 into buf0
  stage(0, 0, 0); stage(0, 1, 0);

#pragma unroll 2
  for (int kt = 0; kt < NKT; ++kt) {
    const int cur = kt & 1, nxt = cur ^ 1;
    const bool more = (kt + 1 < NKT);
    // ---- ph0: k-half 0 ----
    asm volatile("s_waitcnt vmcnt(2)" ::: "memory");   // S0(kt) landed
    __builtin_amdgcn_s_barrier(); SB();
    if (more) stage(kt + 1, 0, nxt);                   // safe: all reads of nxt done
    ldA(0, cur); ldB(0, cur);
    LGKM0(); SB();
    mmac(); SB();
    // ---- ph1: k-half 1 ----
    if (more) { asm volatile("s_waitcnt vmcnt(2)" ::: "memory"); }
    else      { asm volatile("s_waitcnt vmcnt(0)" ::: "memory"); }
    __builtin_amdgcn_s_barrier(); SB();
    if (more) stage(kt + 1, 1, nxt);
    ldA(1, cur); ldB(1, cur);
    LGKM0(); SB();
    mmac(); SB();
  }
#undef SB
#undef LGKM0

  if (MODE == 0) {
    const float* tbrow = epi + bimg * 256;
    float ps[4], ps2[4];
#pragma unroll
    for (int fn = 0; fn < 4; ++fn) { ps[fn] = 0.f; ps2[fn] = 0.f; }
#pragma unroll
    for (int fm = 0; fm < 4; ++fm)
#pragma unroll
      for (int fn = 0; fn < 4; ++fn) {
        int co = wn * 64 + fn * 16 + ln;
        float add = tbrow[co];
#pragma unroll
        for (int i = 0; i < 4; ++i) {
          int m = m_base + wm * 64 + fm * 16 + (l4 << 2) + i;
          float v = acc[fm][fn][i] + add;
          h1out[(size_t)m * 256 + co] = f2bf(v);
          ps[fn] += v; ps2[fn] += v * v;
        }
      }
    // fused GN2 partial stats (channel-group g = co>>3)
#pragma unroll
    for (int fn = 0; fn < 4; ++fn) {
      float s = ps[fn], s2 = ps2[fn];
      s += __shfl_xor(s, 1);  s2 += __shfl_xor(s2, 1);
      s += __shfl_xor(s, 2);  s2 += __shfl_xor(s2, 2);
      s += __shfl_xor(s, 4);  s2 += __shfl_xor(s2, 4);
      s += __shfl_xor(s, 16); s2 += __shfl_xor(s2, 16);
      s += __shfl_xor(s, 32); s2 += __shfl_xor(s2, 32);
      if ((lane & 55) == 0) {                 // lanes 0 and 8
        int g = wn * 8 + fn * 2 + (ln >> 3);
        atomicAdd(&st2sum[bimg * 64 + g * 2 + 0], s);
        atomicAdd(&st2sum[bimg * 64 + g * 2 + 1], s2);
      }
    }
  } else {
    float* tile = (float*)lds;              // [64 co][257] f32 (65.8 KB)
    const int pixb = m_base & 4095;
#pragma unroll
    for (int c = 0; c < 4; ++c) {
      __syncthreads();
      if (wn == c) {
#pragma unroll
        for (int fn = 0; fn < 4; ++fn) {
          int nl = fn * 16 + ln;
          int co = c * 64 + nl;
          float dsc = epi[bimg * 256 + co];
          float scb = sc_b[co];
#pragma unroll
          for (int fm = 0; fm < 4; ++fm)
#pragma unroll
            for (int i = 0; i < 4; ++i) {
              int ml = wm * 64 + fm * 16 + (l4 << 2) + i;
              tile[nl * 257 + ml] = acc[fm][fn][i] * dsc + scb;
            }
        }
      }
      __syncthreads();
#pragma unroll 4
      for (int it = 0; it < 16; ++it) {
        int lin = it * 1024 + tid;
        int co_l = lin >> 8, ml = lin & 255;
        fout[((size_t)(bimg * 256 + c * 64 + co_l)) * 4096 + pixb + ml] =
            tile[co_l * 257 + ml];
      }
    }
  }
}

// ------------------------------- launch -------------------------------
extern "C" void kernel_launch(void* const* d_in, const int* in_sizes, int n_in,
                              void* d_out, int out_size, void* d_ws, size_t ws_size,
                              hipStream_t stream) {
  const float* x       = (const float*)d_in[0];
  const float* temb    = (const float*)d_in[1];
  const float* style   = (const float*)d_in[2];
  const float* gn1_g   = (const float*)d_in[3];
  const float* gn1_b   = (const float*)d_in[4];
  const float* conv1_w = (const float*)d_in[5];
  const float* conv1_b = (const float*)d_in[6];
  const float* temb_w  = (const float*)d_in[7];
  const float* temb_b  = (const float*)d_in[8];
  const float* gn2_g   = (const float*)d_in[9];
  const float* gn2_b   = (const float*)d_in[10];
  const float* style_w = (const float*)d_in[11];
  const float* style_b = (const float*)d_in[12];
  const float* mod_w   = (const float*)d_in[13];
  const float* sc_w    = (const float*)d_in[14];
  const float* sc_b    = (const float*)d_in[15];
  float* out = (float*)d_out;
  char* ws = (char*)d_ws;

  size_t o = 0;
  auto alloc = [&](size_t bytes) { size_t r = o; o += (bytes + 255) & ~(size_t)255; return r; };
  const size_t act1p_bytes = (size_t)32 * HP * WP * 128 * 2;
  const size_t xh_bytes    = (size_t)32 * 64 * 64 * 128 * 2;
  const size_t h1_bytes    = (size_t)32 * 4096 * 256 * 2;
  const size_t act2p_bytes = (size_t)32 * HP * WP * 256 * 2;
  size_t o_act1p = alloc(act1p_bytes);
  size_t o_xh    = alloc(xh_bytes);
  size_t o_h1    = alloc(h1_bytes);
  size_t o_act2p = alloc(act2p_bytes);
  size_t o_w1T   = alloc((size_t)256 * 1152 * 2);
  size_t o_wmT   = alloc((size_t)256 * 2304 * 2);
  size_t o_scTb  = alloc((size_t)32 * 256 * 128 * 2);
  size_t o_tb2   = alloc(8192 * 4);
  size_t o_mvec  = alloc(8192 * 4);
  size_t o_dvec  = alloc(8192 * 4);
  size_t o_SS    = alloc((size_t)256 * 256 * 4);
  size_t o_st1   = alloc(1024 * 8);
  size_t o_st2   = alloc(1024 * 8);
  size_t o_s2sum = alloc(32 * 32 * 2 * 4);
  if (ws_size < o) return;

  u16*    act1p = (u16*)(ws + o_act1p);
  u16*    xh    = (u16*)(ws + o_xh);
  u16*    h1    = (u16*)(ws + o_h1);
  u16*    act2p = (u16*)(ws + o_act2p);
  u16*    w1T   = (u16*)(ws + o_w1T);
  u16*    wmT   = (u16*)(ws + o_wmT);
  u16*    scTb  = (u16*)(ws + o_scTb);
  float*  tb2   = (float*)(ws + o_tb2);
  float*  mvec  = (float*)(ws + o_mvec);
  float*  dvec  = (float*)(ws + o_dvec);
  float*  SS_T  = (float*)(ws + o_SS);
  float2* st1   = (float2*)(ws + o_st1);
  float2* st2   = (float2*)(ws + o_st2);
  float*  s2sum = (float*)(ws + o_s2sum);

  // zero halo borders + GN2 atomic accumulator
  halo_zero_kernel<128><<<(32 * 260 * 16 + 255) / 256, 256, 0, stream>>>(act1p);
  halo_zero_kernel<256><<<(32 * 260 * 32 + 255) / 256, 256, 0, stream>>>(act2p);
  hipMemsetAsync(s2sum, 0, 32 * 32 * 2 * 4, stream);

  repack_w_kernel<<<1152, 256, 0, stream>>>(conv1_w, w1T, 128, 1152, 256 * 1152, 9, 3);
  repack_w_kernel<<<2304, 256, 0, stream>>>(mod_w, wmT, 256, 2304, 256 * 2304, 9, 3);
  modw_ss_kernel<<<256, 256, 0, stream>>>(mod_w, SS_T);
  temb_proj_kernel<<<32, 256, 0, stream>>>(temb, temb_w, temb_b, conv1_b, tb2);
  style_mvec_kernel<<<32, 256, 0, stream>>>(style, style_w, style_b, mvec);
  demod_kernel<<<32, 256, 0, stream>>>(mvec, SS_T, dvec);
  scale_sc_kernel<<<4096, 256, 0, stream>>>(sc_w, dvec, scTb);
  gn1_stats_kernel<<<1024, 256, 0, stream>>>(x, st1);
  gn1_apply_kernel<<<2048, 256, 0, stream>>>(x, st1, gn1_g, gn1_b, act1p, xh);

  igemm_kernel<0><<<512, 1024, 0, stream>>>(act1p, w1T, tb2, nullptr, nullptr,
                                            nullptr, h1, nullptr, s2sum);

  gn2_final_kernel<<<4, 256, 0, stream>>>(s2sum, st2);
  gn2_apply_kernel<<<16384, 256, 0, stream>>>(h1, st2, gn2_g, gn2_b, mvec, act2p);

  igemm_kernel<2><<<512, 1024, 0, stream>>>(act2p, wmT, dvec, xh, scTb,
                                            sc_b, nullptr, out, nullptr);
}

// Round 9
// 532.756 us; speedup vs baseline: 1.2337x; 1.2337x over previous
//
#include <hip/hip_runtime.h>
#include <cstdint>

typedef unsigned short u16;
typedef unsigned int   u32;

typedef __attribute__((ext_vector_type(8))) short bf16x8;
typedef __attribute__((ext_vector_type(4))) float f32x4;

#define DEV __device__ __forceinline__

static constexpr int HP = 66, WP = 66;   // padded spatial

DEV u16 f2bf(float f) {
  u32 u = __float_as_uint(f);
  u32 r = (u + 0x7fffu + ((u >> 16) & 1u)) >> 16;
  return (u16)r;
}
DEV float bf2f(u16 v) { return __uint_as_float((u32)v << 16); }

DEV void gload_lds16(const void* g, void* s) {
  __builtin_amdgcn_global_load_lds(
      (const __attribute__((address_space(1))) void*)g,
      (__attribute__((address_space(3))) void*)s, 16, 0, 0);
}

// ---------------- weight repack: OIHW fp32 -> [co][(ky*3+kx)*Cin+ci] bf16 ----------
__global__ __launch_bounds__(256) void repack_w_kernel(const float* __restrict__ src,
                                                       u16* __restrict__ dst,
                                                       int Cin, int K, int total,
                                                       int ksq, int kdim) {
  for (int idx = blockIdx.x * 256 + threadIdx.x; idx < total; idx += gridDim.x * 256) {
    int co = idx / K;
    int r  = idx - co * K;
    int s  = r / Cin;
    int ci = r - s * Cin;
    int ky = s / kdim, kx = s - ky * kdim;
    dst[idx] = f2bf(src[(co * Cin + ci) * ksq + ky * kdim + kx]);
  }
}

// ---------------- SS_T[i][o] = sum_{kh,kw} mod_w[o][i]^2 ----------------
__global__ __launch_bounds__(256) void modw_ss_kernel(const float* __restrict__ w,
                                                      float* __restrict__ SS_T) {
  int o = blockIdx.x, i = threadIdx.x;
  const float* p = w + (size_t)(o * 256 + i) * 9;
  float s = 0.f;
#pragma unroll
  for (int k = 0; k < 9; ++k) s += p[k] * p[k];
  SS_T[i * 256 + o] = s;
}

// ---------------- mvec[b][i] = style . style_w[i] + style_b[i] + 1 ----------------
__global__ __launch_bounds__(256) void style_mvec_kernel(const float* __restrict__ style,
                                                         const float* __restrict__ style_w,
                                                         const float* __restrict__ style_b,
                                                         float* __restrict__ mvec) {
  __shared__ float st[512];
  int b = blockIdx.x, t = threadIdx.x;
  for (int k = t; k < 512; k += 256) st[k] = style[b * 512 + k];
  __syncthreads();
  const float4* wr = (const float4*)(style_w + t * 512);
  float acc = 0.f;
  for (int k = 0; k < 128; ++k) {
    float4 w4 = wr[k];
    acc += w4.x * st[k*4] + w4.y * st[k*4+1] + w4.z * st[k*4+2] + w4.w * st[k*4+3];
  }
  mvec[b * 256 + t] = acc + style_b[t] + 1.f;
}

// ---------------- dvec[b][o] = rsqrt(sum_i mvec[b][i]^2 * SS_T[i][o] + eps) ---------
__global__ __launch_bounds__(256) void demod_kernel(const float* __restrict__ mvec,
                                                    const float* __restrict__ SS_T,
                                                    float* __restrict__ dvec) {
  __shared__ float m2[256];
  int b = blockIdx.x, t = threadIdx.x;
  float mv = mvec[b * 256 + t];
  m2[t] = mv * mv;
  __syncthreads();
  float acc = 0.f;
  for (int i = 0; i < 256; ++i) acc += m2[i] * SS_T[i * 256 + t];
  dvec[b * 256 + t] = rsqrtf(acc + 1e-8f);
}

// ---------------- scTb[b][co][ci] = sc_w[co][ci] / dvec[b][co]  (bf16) --------------
__global__ __launch_bounds__(256) void scale_sc_kernel(const float* __restrict__ sc_w,
                                                       const float* __restrict__ dvec,
                                                       u16* __restrict__ scTb) {
  int idx = blockIdx.x * 256 + threadIdx.x;   // 32*256*128 total
  int ci = idx & 127;
  int co = (idx >> 7) & 255;
  int b  = idx >> 15;
  scTb[idx] = f2bf(sc_w[co * 128 + ci] / dvec[b * 256 + co]);
}

// ---------------- tb2[b][co] = swish(temb[b]) . temb_w[co] + temb_b + conv1_b -------
__global__ __launch_bounds__(256) void temb_proj_kernel(const float* __restrict__ temb,
                                                        const float* __restrict__ temb_w,
                                                        const float* __restrict__ temb_b,
                                                        const float* __restrict__ conv1_b,
                                                        float* __restrict__ tb2) {
  __shared__ float sw[512];
  int b = blockIdx.x, t = threadIdx.x;
  for (int k = t; k < 512; k += 256) {
    float v = temb[b * 512 + k];
    sw[k] = v / (1.f + __expf(-v));
  }
  __syncthreads();
  const float4* wr = (const float4*)(temb_w + t * 512);
  float acc = 0.f;
  for (int k = 0; k < 128; ++k) {
    float4 w4 = wr[k];
    acc += w4.x * sw[k*4] + w4.y * sw[k*4+1] + w4.z * sw[k*4+2] + w4.w * sw[k*4+3];
  }
  tb2[b * 256 + t] = acc + temb_b[t] + conv1_b[t];
}

// ---------------- halo zero: clear only border pixels of padded NHWC buffer ---------
template <int C>
__global__ __launch_bounds__(256) void halo_zero_kernel(u16* __restrict__ buf) {
  int idx = blockIdx.x * 256 + threadIdx.x;
  const int GR = C / 8;
  if (idx >= 32 * 260 * GR) return;
  int g = idx % GR;
  int p = (idx / GR) % 260;
  int b = idx / (GR * 260);
  int y, x;
  if (p < 66)       { y = 0;        x = p; }
  else if (p < 132) { y = 65;       x = p - 66; }
  else if (p < 196) { y = p - 131;  x = 0; }
  else              { y = p - 195;  x = 65; }
  uint4 z; z.x = 0; z.y = 0; z.z = 0; z.w = 0;
  *(uint4*)(buf + (((size_t)b * HP + y) * WP + x) * C + g * 8) = z;
}

// ---------------- GN1 stats ----------------
__global__ __launch_bounds__(256) void gn1_stats_kernel(const float* __restrict__ x,
                                                        float2* __restrict__ st1) {
  int bg = blockIdx.x;
  const float4* p = (const float4*)(x + (size_t)bg * 16384);
  float s = 0.f, s2 = 0.f;
  for (int i = threadIdx.x; i < 4096; i += 256) {
    float4 v = p[i];
    s  += v.x + v.y + v.z + v.w;
    s2 += v.x*v.x + v.y*v.y + v.z*v.z + v.w*v.w;
  }
  for (int d = 32; d; d >>= 1) { s += __shfl_down(s, d); s2 += __shfl_down(s2, d); }
  __shared__ float red[2][4];
  if ((threadIdx.x & 63) == 0) { red[0][threadIdx.x >> 6] = s; red[1][threadIdx.x >> 6] = s2; }
  __syncthreads();
  if (threadIdx.x == 0) {
    s  = red[0][0] + red[0][1] + red[0][2] + red[0][3];
    s2 = red[1][0] + red[1][1] + red[1][2] + red[1][3];
    float mean = s / 16384.f;
    float var  = s2 / 16384.f - mean * mean;
    st1[bg] = make_float2(mean, rsqrtf(var + 1e-5f));
  }
}

// ---------------- GN1 apply + swish -> act1p (padded NHWC bf16); also x -> xh NHWC --
__global__ __launch_bounds__(256) void gn1_apply_kernel(const float* __restrict__ x,
                                                        const float2* __restrict__ st1,
                                                        const float* __restrict__ g1,
                                                        const float* __restrict__ b1,
                                                        u16* __restrict__ act1p,
                                                        u16* __restrict__ xh) {
  __shared__ float xs[128][65];
  int blk = blockIdx.x;
  int b = blk >> 6, y = blk & 63;
  int t = threadIdx.x;
#pragma unroll 8
  for (int pass = 0; pass < 32; ++pass) {
    int c = pass * 4 + (t >> 6);
    xs[c][t & 63] = x[(((size_t)b * 128 + c) * 64 + y) * 64 + (t & 63)];
  }
  __syncthreads();
  for (int pass = 0; pass < 32; ++pass) {
    int xc = pass * 2 + (t >> 7);
    int c  = t & 127;
    float v = xs[c][xc];
    float2 ms = st1[b * 32 + (c >> 2)];
    float vn = (v - ms.x) * ms.y * g1[c] + b1[c];
    float sw = vn / (1.f + __expf(-vn));
    act1p[(((size_t)b * HP + (y + 1)) * WP + (xc + 1)) * 128 + c] = f2bf(sw);
    xh[(((size_t)b * 64 + y) * 64 + xc) * 128 + c] = f2bf(v);
  }
}

// -- GN2 apply (stats inline from totals) + swish + in-channel mod: h1 -> act2p ------
__global__ __launch_bounds__(256) void gn2_apply_kernel(const u16* __restrict__ h1,
                                                        const float* __restrict__ st2sum,
                                                        const float* __restrict__ g2,
                                                        const float* __restrict__ b2,
                                                        const float* __restrict__ mvec,
                                                        u16* __restrict__ act2p) {
  int idx = blockIdx.x * 256 + threadIdx.x;  // granule id
  int gpix = idx >> 5;
  int gi = idx & 31;
  int c0 = gi * 8;
  int b = gpix >> 12, y = (gpix >> 6) & 63, x = gpix & 63;
  uint4 raw = *(const uint4*)(h1 + (size_t)gpix * 256 + c0);
  const u16* rs = (const u16*)&raw;
  float s  = st2sum[b * 64 + gi * 2];
  float s2 = st2sum[b * 64 + gi * 2 + 1];
  float mean = s / 32768.f;
  float rstd = rsqrtf(s2 / 32768.f - mean * mean + 1e-5f);
  const float* mv = mvec + b * 256 + c0;
  u16 outp[8];
#pragma unroll
  for (int e = 0; e < 8; ++e) {
    float v  = bf2f(rs[e]);
    float vn = (v - mean) * rstd * g2[c0 + e] + b2[c0 + e];
    float sw = vn / (1.f + __expf(-vn));
    outp[e] = f2bf(sw * mv[e]);
  }
  *(uint4*)(act2p + (((size_t)b * HP + (y + 1)) * WP + (x + 1)) * 256 + c0) = *(const uint4*)outp;
}

// ---- implicit-GEMM conv: 256x256 tile, 16 waves (4x4), BK=64, 2 phases by k-half ---
// LDS per buffer (64KB): [A0|A1|B0|B1] 16KB sub-tiles, each [256 rows][64B].
// Conflict-free swizzle: phys granule c at row r holds logical granule
// (c-(r>>2))&3; read uses c=(l4+(row>>2))&3 -> every bank 2-way max (free, m136).
// Phase = { vmcnt(2); barrier; stage k-half of kt+1 into other buf (linear dest,
// inverse-permuted source); 4+4 ds_read_b128; lgkmcnt(0); 16 MFMA (setprio) }.
// MODE 0: conv1 -> h1 bf16 NHWC + fused GN2 partial stats.
// MODE 2: modconv + fused 1x1 shortcut -> d_out NCHW fp32 = acc*dvec + sc_b.
template <int MODE>
__global__ __launch_bounds__(1024, 4) void igemm_kernel(const u16* __restrict__ act,
                                                        const u16* __restrict__ wT,
                                                        const float* __restrict__ epi,
                                                        const u16* __restrict__ xh,
                                                        const u16* __restrict__ scTb,
                                                        const float* __restrict__ sc_b,
                                                        u16* __restrict__ h1out,
                                                        float* __restrict__ fout,
                                                        float* __restrict__ st2sum) {
  constexpr int CIN    = (MODE == 0) ? 128 : 256;
  constexpr int NSUB   = CIN / 64;
  constexpr int KW     = CIN * 9;
  constexpr int NKMAIN = KW / 64;                 // 18 / 36
  constexpr int NKT    = (MODE == 2) ? NKMAIN + 2 : NKMAIN;

  __shared__ __align__(16) unsigned char lds[131072];
  const int tid  = threadIdx.x;
  const int wave = tid >> 6, lane = tid & 63;
  const int wm = wave >> 2, wn = wave & 3;        // 4 x 4 waves
  const int m_base = blockIdx.x * 256;
  const int bimg = m_base >> 12;
  const int ln = lane & 15, l4 = lane >> 4;

  // staging constants: wave stages rows [wave*16, +16); lane -> (srow, phys col c)
  const int srow = lane >> 2;                     // 0..15
  const int cphys = lane & 3;
  const int r_st  = wave * 16 + srow;             // 0..255
  const int gl    = (cphys - (r_st >> 2)) & 3;    // logical granule this lane loads

  u32 pixA, pixX = 0, rowB, rowS = 0;
  {
    int m = m_base + r_st;
    int y = (m >> 6) & 63, x = m & 63;
    pixA = (u32)((bimg * HP + y) * WP + x) * CIN + gl * 8;
    if (MODE == 2) pixX = (u32)m * 128 + gl * 8;
    rowB = (u32)r_st * KW + gl * 8;
    if (MODE == 2) rowS = (u32)(bimg * 256 + r_st) * 128 + gl * 8;
  }

  f32x4 acc[4][4];
#pragma unroll
  for (int i = 0; i < 4; ++i)
#pragma unroll
    for (int j = 0; j < 4; ++j) acc[i][j] = (f32x4){0.f, 0.f, 0.f, 0.f};

  // stage k-half h of tile kt into buffer buf (1 A-load + 1 B-load per thread)
  auto stage = [&](int kt, int h, int buf) {
    unsigned char* dstA = lds + buf * 65536 + h * 16384 + wave * 1024;
    unsigned char* dstB = lds + buf * 65536 + 32768 + h * 16384 + wave * 1024;
    if (MODE == 2 && kt >= NKMAIN) {
      u32 ko = (u32)(kt - NKMAIN) * 64 + h * 32;
      gload_lds16(xh   + pixX + ko, dstA);
      gload_lds16(scTb + rowS + ko, dstB);
    } else {
      int tap = kt / NSUB;
      int kin = (kt - tap * NSUB) * 64 + h * 32;
      int ky = tap / 3, kx = tap - ky * 3;
      u32 koA = (u32)((ky * WP + kx) * CIN + kin);
      gload_lds16(act + pixA + koA, dstA);
      gload_lds16(wT  + rowB + (u32)(kt * 64 + h * 32), dstB);
    }
  };

  bf16x8 af[4], bf[4];
  auto ldA = [&](int kk, int buf) {
    const unsigned char* As = lds + buf * 65536 + kk * 16384;
    int c = (l4 + (ln >> 2)) & 3;                 // = (l4 + (row>>2)) & 3
    const unsigned char* base = As + (wm * 64 + ln) * 64 + c * 16;
#pragma unroll
    for (int f = 0; f < 4; ++f)
      af[f] = *(const bf16x8*)(base + f * 1024);  // f*16 rows * 64B
  };
  auto ldB = [&](int kk, int buf) {
    const unsigned char* Bs = lds + buf * 65536 + 32768 + kk * 16384;
    int c = (l4 + (ln >> 2)) & 3;
    const unsigned char* base = Bs + (wn * 64 + ln) * 64 + c * 16;
#pragma unroll
    for (int f = 0; f < 4; ++f)
      bf[f] = *(const bf16x8*)(base + f * 1024);
  };
  auto mmac = [&]() {
    __builtin_amdgcn_s_setprio(1);
#pragma unroll
    for (int f = 0; f < 4; ++f)
#pragma unroll
      for (int f1 = 0; f1 < 4; ++f1)
        acc[f][f1] = __builtin_amdgcn_mfma_f32_16x16x32_bf16(af[f], bf[f1],
                                                             acc[f][f1], 0, 0, 0);
    __builtin_amdgcn_s_setprio(0);
  };

#define SB() __builtin_amdgcn_sched_barrier(0)
#define LGKM0() asm volatile("s_waitcnt lgkmcnt(0)" ::: "memory")

  // prologue: both k-halves of tile 0 into buf0
  stage(0, 0, 0); stage(0, 1, 0);

#pragma unroll 2
  for (int kt = 0; kt < NKT; ++kt) {
    const int cur = kt & 1, nxt = cur ^ 1;
    const bool more = (kt + 1 < NKT);
    // ---- ph0: k-half 0 ----
    asm volatile("s_waitcnt vmcnt(2)" ::: "memory");   // S(kt,0) landed
    __builtin_amdgcn_s_barrier(); SB();
    if (more) stage(kt + 1, 0, nxt);                   // nxt fully consumed 2 bars ago
    ldA(0, cur); ldB(0, cur);
    LGKM0(); SB();
    mmac(); SB();
    // ---- ph1: k-half 1 ----
    if (more) { asm volatile("s_waitcnt vmcnt(2)" ::: "memory"); }
    else      { asm volatile("s_waitcnt vmcnt(0)" ::: "memory"); }
    __builtin_amdgcn_s_barrier(); SB();
    if (more) stage(kt + 1, 1, nxt);
    ldA(1, cur); ldB(1, cur);
    LGKM0(); SB();
    mmac(); SB();
  }
#undef SB
#undef LGKM0

  if (MODE == 0) {
    const float* tbrow = epi + bimg * 256;
    float ps[4], ps2[4];
#pragma unroll
    for (int fn = 0; fn < 4; ++fn) { ps[fn] = 0.f; ps2[fn] = 0.f; }
#pragma unroll
    for (int fm = 0; fm < 4; ++fm)
#pragma unroll
      for (int fn = 0; fn < 4; ++fn) {
        int co = wn * 64 + fn * 16 + ln;
        float add = tbrow[co];
#pragma unroll
        for (int i = 0; i < 4; ++i) {
          int m = m_base + wm * 64 + fm * 16 + (l4 << 2) + i;
          float v = acc[fm][fn][i] + add;
          h1out[(size_t)m * 256 + co] = f2bf(v);
          ps[fn] += v; ps2[fn] += v * v;
        }
      }
    // fused GN2 partial stats (channel-group g = co>>3)
#pragma unroll
    for (int fn = 0; fn < 4; ++fn) {
      float s = ps[fn], s2 = ps2[fn];
      s += __shfl_xor(s, 1);  s2 += __shfl_xor(s2, 1);
      s += __shfl_xor(s, 2);  s2 += __shfl_xor(s2, 2);
      s += __shfl_xor(s, 4);  s2 += __shfl_xor(s2, 4);
      s += __shfl_xor(s, 16); s2 += __shfl_xor(s2, 16);
      s += __shfl_xor(s, 32); s2 += __shfl_xor(s2, 32);
      if ((lane & 55) == 0) {                 // lanes 0 and 8
        int g = wn * 8 + fn * 2 + (ln >> 3);
        atomicAdd(&st2sum[bimg * 64 + g * 2 + 0], s);
        atomicAdd(&st2sum[bimg * 64 + g * 2 + 1], s2);
      }
    }
  } else {
    float* tile = (float*)lds;              // [64 co][257] f32 (65.8 KB)
    const int pixb = m_base & 4095;
#pragma unroll
    for (int c = 0; c < 4; ++c) {
      __syncthreads();
      if (wn == c) {
#pragma unroll
        for (int fn = 0; fn < 4; ++fn) {
          int nl = fn * 16 + ln;
          int co = c * 64 + nl;
          float dsc = epi[bimg * 256 + co];
          float scb = sc_b[co];
#pragma unroll
          for (int fm = 0; fm < 4; ++fm)
#pragma unroll
            for (int i = 0; i < 4; ++i) {
              int ml = wm * 64 + fm * 16 + (l4 << 2) + i;
              tile[nl * 257 + ml] = acc[fm][fn][i] * dsc + scb;
            }
        }
      }
      __syncthreads();
#pragma unroll 4
      for (int it = 0; it < 16; ++it) {
        int lin = it * 1024 + tid;
        int co_l = lin >> 8, ml = lin & 255;
        fout[((size_t)(bimg * 256 + c * 64 + co_l)) * 4096 + pixb + ml] =
            tile[co_l * 257 + ml];
      }
    }
  }
}

// ------------------------------- launch -------------------------------
extern "C" void kernel_launch(void* const* d_in, const int* in_sizes, int n_in,
                              void* d_out, int out_size, void* d_ws, size_t ws_size,
                              hipStream_t stream) {
  const float* x       = (const float*)d_in[0];
  const float* temb    = (const float*)d_in[1];
  const float* style   = (const float*)d_in[2];
  const float* gn1_g   = (const float*)d_in[3];
  const float* gn1_b   = (const float*)d_in[4];
  const float* conv1_w = (const float*)d_in[5];
  const float* conv1_b = (const float*)d_in[6];
  const float* temb_w  = (const float*)d_in[7];
  const float* temb_b  = (const float*)d_in[8];
  const float* gn2_g   = (const float*)d_in[9];
  const float* gn2_b   = (const float*)d_in[10];
  const float* style_w = (const float*)d_in[11];
  const float* style_b = (const float*)d_in[12];
  const float* mod_w   = (const float*)d_in[13];
  const float* sc_w    = (const float*)d_in[14];
  const float* sc_b    = (const float*)d_in[15];
  float* out = (float*)d_out;
  char* ws = (char*)d_ws;

  size_t o = 0;
  auto alloc = [&](size_t bytes) { size_t r = o; o += (bytes + 255) & ~(size_t)255; return r; };
  const size_t act1p_bytes = (size_t)32 * HP * WP * 128 * 2;
  const size_t xh_bytes    = (size_t)32 * 64 * 64 * 128 * 2;
  const size_t h1_bytes    = (size_t)32 * 4096 * 256 * 2;
  const size_t act2p_bytes = (size_t)32 * HP * WP * 256 * 2;
  size_t o_act1p = alloc(act1p_bytes);
  size_t o_xh    = alloc(xh_bytes);
  size_t o_h1    = alloc(h1_bytes);
  size_t o_act2p = alloc(act2p_bytes);
  size_t o_w1T   = alloc((size_t)256 * 1152 * 2);
  size_t o_wmT   = alloc((size_t)256 * 2304 * 2);
  size_t o_scTb  = alloc((size_t)32 * 256 * 128 * 2);
  size_t o_tb2   = alloc(8192 * 4);
  size_t o_mvec  = alloc(8192 * 4);
  size_t o_dvec  = alloc(8192 * 4);
  size_t o_SS    = alloc((size_t)256 * 256 * 4);
  size_t o_st1   = alloc(1024 * 8);
  size_t o_s2sum = alloc(32 * 32 * 2 * 4);
  if (ws_size < o) return;

  u16*    act1p = (u16*)(ws + o_act1p);
  u16*    xh    = (u16*)(ws + o_xh);
  u16*    h1    = (u16*)(ws + o_h1);
  u16*    act2p = (u16*)(ws + o_act2p);
  u16*    w1T   = (u16*)(ws + o_w1T);
  u16*    wmT   = (u16*)(ws + o_wmT);
  u16*    scTb  = (u16*)(ws + o_scTb);
  float*  tb2   = (float*)(ws + o_tb2);
  float*  mvec  = (float*)(ws + o_mvec);
  float*  dvec  = (float*)(ws + o_dvec);
  float*  SS_T  = (float*)(ws + o_SS);
  float2* st1   = (float2*)(ws + o_st1);
  float*  s2sum = (float*)(ws + o_s2sum);

  // zero halo borders + GN2 atomic accumulator
  halo_zero_kernel<128><<<(32 * 260 * 16 + 255) / 256, 256, 0, stream>>>(act1p);
  halo_zero_kernel<256><<<(32 * 260 * 32 + 255) / 256, 256, 0, stream>>>(act2p);
  hipMemsetAsync(s2sum, 0, 32 * 32 * 2 * 4, stream);

  repack_w_kernel<<<1152, 256, 0, stream>>>(conv1_w, w1T, 128, 1152, 256 * 1152, 9, 3);
  repack_w_kernel<<<2304, 256, 0, stream>>>(mod_w, wmT, 256, 2304, 256 * 2304, 9, 3);
  modw_ss_kernel<<<256, 256, 0, stream>>>(mod_w, SS_T);
  temb_proj_kernel<<<32, 256, 0, stream>>>(temb, temb_w, temb_b, conv1_b, tb2);
  style_mvec_kernel<<<32, 256, 0, stream>>>(style, style_w, style_b, mvec);
  demod_kernel<<<32, 256, 0, stream>>>(mvec, SS_T, dvec);
  scale_sc_kernel<<<4096, 256, 0, stream>>>(sc_w, dvec, scTb);
  gn1_stats_kernel<<<1024, 256, 0, stream>>>(x, st1);
  gn1_apply_kernel<<<2048, 256, 0, stream>>>(x, st1, gn1_g, gn1_b, act1p, xh);

  igemm_kernel<0><<<512, 1024, 0, stream>>>(act1p, w1T, tb2, nullptr, nullptr,
                                            nullptr, h1, nullptr, s2sum);

  gn2_apply_kernel<<<16384, 256, 0, stream>>>(h1, s2sum, gn2_g, gn2_b, mvec, act2p);

  igemm_kernel<2><<<512, 1024, 0, stream>>>(act2p, wmT, dvec, xh, scTb,
                                            sc_b, nullptr, out, nullptr);
}

// Round 10
// 514.746 us; speedup vs baseline: 1.2769x; 1.0350x over previous
//
#include <hip/hip_runtime.h>
#include <cstdint>

typedef unsigned short u16;
typedef unsigned int   u32;

typedef __attribute__((ext_vector_type(8))) short bf16x8;
typedef __attribute__((ext_vector_type(4))) float f32x4;

#define DEV __device__ __forceinline__

static constexpr int HP = 66, WP = 66;   // padded spatial

DEV u16 f2bf(float f) {
  u32 u = __float_as_uint(f);
  u32 r = (u + 0x7fffu + ((u >> 16) & 1u)) >> 16;
  return (u16)r;
}
DEV float bf2f(u16 v) { return __uint_as_float((u32)v << 16); }

DEV void gload_lds16(const void* g, void* s) {
  __builtin_amdgcn_global_load_lds(
      (const __attribute__((address_space(1))) void*)g,
      (__attribute__((address_space(3))) void*)s, 16, 0, 0);
}

// ---------------- weight repack: OIHW fp32 -> [co][(ky*3+kx)*Cin+ci] bf16 ----------
__global__ __launch_bounds__(256) void repack_w_kernel(const float* __restrict__ src,
                                                       u16* __restrict__ dst,
                                                       int Cin, int K, int total,
                                                       int ksq, int kdim) {
  for (int idx = blockIdx.x * 256 + threadIdx.x; idx < total; idx += gridDim.x * 256) {
    int co = idx / K;
    int r  = idx - co * K;
    int s  = r / Cin;
    int ci = r - s * Cin;
    int ky = s / kdim, kx = s - ky * kdim;
    dst[idx] = f2bf(src[(co * Cin + ci) * ksq + ky * kdim + kx]);
  }
}

// ---------------- SS_T[i][o] = sum_{kh,kw} mod_w[o][i]^2 ----------------
__global__ __launch_bounds__(256) void modw_ss_kernel(const float* __restrict__ w,
                                                      float* __restrict__ SS_T) {
  int o = blockIdx.x, i = threadIdx.x;
  const float* p = w + (size_t)(o * 256 + i) * 9;
  float s = 0.f;
#pragma unroll
  for (int k = 0; k < 9; ++k) s += p[k] * p[k];
  SS_T[i * 256 + o] = s;
}

// ---------------- mvec[b][i] = style . style_w[i] + style_b[i] + 1 ----------------
__global__ __launch_bounds__(256) void style_mvec_kernel(const float* __restrict__ style,
                                                         const float* __restrict__ style_w,
                                                         const float* __restrict__ style_b,
                                                         float* __restrict__ mvec) {
  __shared__ float st[512];
  int b = blockIdx.x, t = threadIdx.x;
  for (int k = t; k < 512; k += 256) st[k] = style[b * 512 + k];
  __syncthreads();
  const float4* wr = (const float4*)(style_w + t * 512);
  float acc = 0.f;
  for (int k = 0; k < 128; ++k) {
    float4 w4 = wr[k];
    acc += w4.x * st[k*4] + w4.y * st[k*4+1] + w4.z * st[k*4+2] + w4.w * st[k*4+3];
  }
  mvec[b * 256 + t] = acc + style_b[t] + 1.f;
}

// ---------------- dvec[b][o] = rsqrt(sum_i mvec[b][i]^2 * SS_T[i][o] + eps) ---------
__global__ __launch_bounds__(256) void demod_kernel(const float* __restrict__ mvec,
                                                    const float* __restrict__ SS_T,
                                                    float* __restrict__ dvec) {
  __shared__ float m2[256];
  int b = blockIdx.x, t = threadIdx.x;
  float mv = mvec[b * 256 + t];
  m2[t] = mv * mv;
  __syncthreads();
  float acc = 0.f;
  for (int i = 0; i < 256; ++i) acc += m2[i] * SS_T[i * 256 + t];
  dvec[b * 256 + t] = rsqrtf(acc + 1e-8f);
}

// ---------------- scTb[b][co][ci] = sc_w[co][ci] / dvec[b][co]  (bf16) --------------
__global__ __launch_bounds__(256) void scale_sc_kernel(const float* __restrict__ sc_w,
                                                       const float* __restrict__ dvec,
                                                       u16* __restrict__ scTb) {
  int idx = blockIdx.x * 256 + threadIdx.x;   // 32*256*128 total
  int ci = idx & 127;
  int co = (idx >> 7) & 255;
  int b  = idx >> 15;
  scTb[idx] = f2bf(sc_w[co * 128 + ci] / dvec[b * 256 + co]);
}

// ---------------- tb2[b][co] = swish(temb[b]) . temb_w[co] + temb_b + conv1_b -------
__global__ __launch_bounds__(256) void temb_proj_kernel(const float* __restrict__ temb,
                                                        const float* __restrict__ temb_w,
                                                        const float* __restrict__ temb_b,
                                                        const float* __restrict__ conv1_b,
                                                        float* __restrict__ tb2) {
  __shared__ float sw[512];
  int b = blockIdx.x, t = threadIdx.x;
  for (int k = t; k < 512; k += 256) {
    float v = temb[b * 512 + k];
    sw[k] = v / (1.f + __expf(-v));
  }
  __syncthreads();
  const float4* wr = (const float4*)(temb_w + t * 512);
  float acc = 0.f;
  for (int k = 0; k < 128; ++k) {
    float4 w4 = wr[k];
    acc += w4.x * sw[k*4] + w4.y * sw[k*4+1] + w4.z * sw[k*4+2] + w4.w * sw[k*4+3];
  }
  tb2[b * 256 + t] = acc + temb_b[t] + conv1_b[t];
}

// ---------------- halo zero: clear only border pixels of padded NHWC buffer ---------
template <int C>
__global__ __launch_bounds__(256) void halo_zero_kernel(u16* __restrict__ buf) {
  int idx = blockIdx.x * 256 + threadIdx.x;
  const int GR = C / 8;
  if (idx >= 32 * 260 * GR) return;
  int g = idx % GR;
  int p = (idx / GR) % 260;
  int b = idx / (GR * 260);
  int y, x;
  if (p < 66)       { y = 0;        x = p; }
  else if (p < 132) { y = 65;       x = p - 66; }
  else if (p < 196) { y = p - 131;  x = 0; }
  else              { y = p - 195;  x = 65; }
  uint4 z; z.x = 0; z.y = 0; z.z = 0; z.w = 0;
  *(uint4*)(buf + (((size_t)b * HP + y) * WP + x) * C + g * 8) = z;
}

// ---------------- GN1 stats ----------------
__global__ __launch_bounds__(256) void gn1_stats_kernel(const float* __restrict__ x,
                                                        float2* __restrict__ st1) {
  int bg = blockIdx.x;
  const float4* p = (const float4*)(x + (size_t)bg * 16384);
  float s = 0.f, s2 = 0.f;
  for (int i = threadIdx.x; i < 4096; i += 256) {
    float4 v = p[i];
    s  += v.x + v.y + v.z + v.w;
    s2 += v.x*v.x + v.y*v.y + v.z*v.z + v.w*v.w;
  }
  for (int d = 32; d; d >>= 1) { s += __shfl_down(s, d); s2 += __shfl_down(s2, d); }
  __shared__ float red[2][4];
  if ((threadIdx.x & 63) == 0) { red[0][threadIdx.x >> 6] = s; red[1][threadIdx.x >> 6] = s2; }
  __syncthreads();
  if (threadIdx.x == 0) {
    s  = red[0][0] + red[0][1] + red[0][2] + red[0][3];
    s2 = red[1][0] + red[1][1] + red[1][2] + red[1][3];
    float mean = s / 16384.f;
    float var  = s2 / 16384.f - mean * mean;
    st1[bg] = make_float2(mean, rsqrtf(var + 1e-5f));
  }
}

// ---------------- GN1 apply + swish -> act1p (padded NHWC bf16); also x -> xh NHWC --
__global__ __launch_bounds__(256) void gn1_apply_kernel(const float* __restrict__ x,
                                                        const float2* __restrict__ st1,
                                                        const float* __restrict__ g1,
                                                        const float* __restrict__ b1,
                                                        u16* __restrict__ act1p,
                                                        u16* __restrict__ xh) {
  __shared__ float xs[128][65];
  int blk = blockIdx.x;
  int b = blk >> 6, y = blk & 63;
  int t = threadIdx.x;
#pragma unroll 8
  for (int pass = 0; pass < 32; ++pass) {
    int c = pass * 4 + (t >> 6);
    xs[c][t & 63] = x[(((size_t)b * 128 + c) * 64 + y) * 64 + (t & 63)];
  }
  __syncthreads();
  for (int pass = 0; pass < 32; ++pass) {
    int xc = pass * 2 + (t >> 7);
    int c  = t & 127;
    float v = xs[c][xc];
    float2 ms = st1[b * 32 + (c >> 2)];
    float vn = (v - ms.x) * ms.y * g1[c] + b1[c];
    float sw = vn / (1.f + __expf(-vn));
    act1p[(((size_t)b * HP + (y + 1)) * WP + (xc + 1)) * 128 + c] = f2bf(sw);
    xh[(((size_t)b * 64 + y) * 64 + xc) * 128 + c] = f2bf(v);
  }
}

// -- GN2 apply (stats inline from totals) + swish + in-channel mod: h1 -> act2p ------
__global__ __launch_bounds__(256) void gn2_apply_kernel(const u16* __restrict__ h1,
                                                        const float* __restrict__ st2sum,
                                                        const float* __restrict__ g2,
                                                        const float* __restrict__ b2,
                                                        const float* __restrict__ mvec,
                                                        u16* __restrict__ act2p) {
  int idx = blockIdx.x * 256 + threadIdx.x;  // granule id
  int gpix = idx >> 5;
  int gi = idx & 31;
  int c0 = gi * 8;
  int b = gpix >> 12, y = (gpix >> 6) & 63, x = gpix & 63;
  uint4 raw = *(const uint4*)(h1 + (size_t)gpix * 256 + c0);
  const u16* rs = (const u16*)&raw;
  float s  = st2sum[b * 64 + gi * 2];
  float s2 = st2sum[b * 64 + gi * 2 + 1];
  float mean = s / 32768.f;
  float rstd = rsqrtf(s2 / 32768.f - mean * mean + 1e-5f);
  const float* mv = mvec + b * 256 + c0;
  u16 outp[8];
#pragma unroll
  for (int e = 0; e < 8; ++e) {
    float v  = bf2f(rs[e]);
    float vn = (v - mean) * rstd * g2[c0 + e] + b2[c0 + e];
    float sw = vn / (1.f + __expf(-vn));
    outp[e] = f2bf(sw * mv[e]);
  }
  *(uint4*)(act2p + (((size_t)b * HP + (y + 1)) * WP + (x + 1)) * 256 + c0) = *(const uint4*)outp;
}

// ---------- implicit-GEMM conv: 256x256 tile, 8 waves, BK=64, 4-phase schedule ------
// Round-7 skeleton + 10-slot LDS ring (10 x 16KB half-tiles = 160KB).
// Half index H = 4kt+j (j: 0=Ah0,1=Bg0,2=Bg1,3=Ah1); slot = H%10.
// Phase = { vmcnt(10); barrier; stage ONE half (lead 5-7 halves); ds_read frags;
//           MFMA (compiler-counted lgkmcnt) }. Stage pattern: ph0->Ah1(kt+1),
// ph1->Ah0(kt+2), ph2->Bg0(kt+2), ph3->Bg1(kt+2). Tail: 2 tiles peeled,
// vmcnt 10,10,8,-,4,2,0,-. Restage safety: every overwritten slot was last read
// >=1 barrier before the (post-barrier) stage, incl. ph3's Bg0 re-read.
template <int MODE>
__global__ __launch_bounds__(512, 2) void igemm_kernel(const u16* __restrict__ act,
                                                       const u16* __restrict__ wT,
                                                       const float* __restrict__ epi,
                                                       const u16* __restrict__ xh,
                                                       const u16* __restrict__ scTb,
                                                       const float* __restrict__ sc_b,
                                                       u16* __restrict__ h1out,
                                                       float* __restrict__ fout,
                                                       float* __restrict__ st2sum) {
  constexpr int CIN    = (MODE == 0) ? 128 : 256;
  constexpr int NSUB   = CIN / 64;
  constexpr int KW     = CIN * 9;
  constexpr int NKMAIN = KW / 64;                 // 18 / 36
  constexpr int NKT    = (MODE == 2) ? NKMAIN + 2 : NKMAIN;

  __shared__ __align__(16) unsigned char lds[163840];   // 10 x 16KB ring
  const int tid  = threadIdx.x;
  const int wave = tid >> 6, lane = tid & 63;
  const int wm = wave >> 2, wn = wave & 3;        // 2 x 4 waves
  const int m_base = blockIdx.x * 256;
  const int bimg = m_base >> 12;
  const int ln = lane & 15, l4 = lane >> 4;

  // staging lane constants (identical mapping to round 7)
  const int srow = lane >> 3;                     // 0..7
  const int glog = (lane & 7) ^ srow;             // pre-swizzled source granule

  u32 pixA[2][2], pixX[2][2], rowB[2][2], rowS[2][2];
#pragma unroll
  for (int j = 0; j < 2; ++j)
#pragma unroll
    for (int h = 0; h < 2; ++h) {
      int mlocal = (wave & 3) * 16 + j * 8 + srow + h * 64 + (wave >> 2) * 128;
      int m = m_base + mlocal;
      int y = (m >> 6) & 63, x = m & 63;
      pixA[j][h] = (u32)((bimg * HP + y) * WP + x) * CIN + glog * 8;
      if (MODE == 2) pixX[j][h] = (u32)m * 128 + glog * 8;
      int co = (wave >> 1) * 64 + h * 32 + (wave & 1) * 16 + j * 8 + srow;
      rowB[j][h] = (u32)co * KW + glog * 8;
      if (MODE == 2) rowS[j][h] = (u32)(bimg * 256 + co) * 128 + glog * 8;
    }

  f32x4 acc[8][4];
#pragma unroll
  for (int i = 0; i < 8; ++i)
#pragma unroll
    for (int j = 0; j < 4; ++j) acc[i][j] = (f32x4){0.f, 0.f, 0.f, 0.f};

  auto stageA = [&](int kt, int h, int slotbyte) {
    unsigned char* dst = lds + slotbyte + wave * 2048;
    if (MODE == 2 && kt >= NKMAIN) {
      u32 ko = (u32)(kt - NKMAIN) * 64;
      gload_lds16(xh + pixX[0][h] + ko, dst);
      gload_lds16(xh + pixX[1][h] + ko, dst + 1024);
    } else {
      int tap = kt / NSUB;
      int kin = (kt - tap * NSUB) * 64;
      int ky = tap / 3, kx = tap - ky * 3;
      u32 ko = (u32)((ky * WP + kx) * CIN + kin);
      gload_lds16(act + pixA[0][h] + ko, dst);
      gload_lds16(act + pixA[1][h] + ko, dst + 1024);
    }
  };
  auto stageB = [&](int kt, int g, int slotbyte) {
    unsigned char* dst = lds + slotbyte + wave * 2048;
    if (MODE == 2 && kt >= NKMAIN) {
      u32 ko = (u32)(kt - NKMAIN) * 64;
      gload_lds16(scTb + rowS[0][g] + ko, dst);
      gload_lds16(scTb + rowS[1][g] + ko, dst + 1024);
    } else {
      u32 ko = (u32)kt * 64;
      gload_lds16(wT + rowB[0][g] + ko, dst);
      gload_lds16(wT + rowB[1][g] + ko, dst + 1024);
    }
  };

  bf16x8 af[8], bf[4];
  auto ldA = [&](int slotbyte) {
    const unsigned char* As = lds + slotbyte;
#pragma unroll
    for (int f = 0; f < 4; ++f)
#pragma unroll
      for (int kk = 0; kk < 2; ++kk) {
        int lr = wm * 64 + f * 16 + ln;               // local row in half-tile
        int gr = (kk * 4 + l4) ^ (lr & 7);
        af[f * 2 + kk] = *(const bf16x8*)(As + lr * 128 + gr * 16);
      }
  };
  auto ldB = [&](int slotbyte) {
    const unsigned char* Bs = lds + slotbyte;
#pragma unroll
    for (int f1 = 0; f1 < 2; ++f1)
#pragma unroll
      for (int kk = 0; kk < 2; ++kk) {
        int lr = wn * 32 + f1 * 16 + ln;
        int gr = (kk * 4 + l4) ^ (lr & 7);
        bf[f1 * 2 + kk] = *(const bf16x8*)(Bs + lr * 128 + gr * 16);
      }
  };
  auto mmac = [&](int h, int g) {
    __builtin_amdgcn_s_setprio(1);
#pragma unroll
    for (int f = 0; f < 4; ++f)
#pragma unroll
      for (int f1 = 0; f1 < 2; ++f1)
#pragma unroll
        for (int kk = 0; kk < 2; ++kk)
          acc[h * 4 + f][g * 2 + f1] = __builtin_amdgcn_mfma_f32_16x16x32_bf16(
              af[f * 2 + kk], bf[f1 * 2 + kk], acc[h * 4 + f][g * 2 + f1], 0, 0, 0);
    __builtin_amdgcn_s_setprio(0);
  };

#define PHASE_BAR() do { __builtin_amdgcn_sched_barrier(0); \
    __builtin_amdgcn_s_barrier(); __builtin_amdgcn_sched_barrier(0); } while (0)
#define VMC(n) asm volatile("s_waitcnt vmcnt(" #n ")" ::: "memory")

  // prologue: halves 0..6 -> slots 0..6 (tile0 all; tile1 Ah0,Bg0,Bg1)
  stageA(0, 0, 0 * 16384); stageB(0, 0, 1 * 16384);
  stageB(0, 1, 2 * 16384); stageA(0, 1, 3 * 16384);
  stageA(1, 0, 4 * 16384); stageB(1, 0, 5 * 16384); stageB(1, 1, 6 * 16384);

  auto md = [](int x) { return x >= 10 ? x - 10 : x; };

  int sb = 0;                                     // (4*kt) % 10
#pragma unroll 2
  for (int kt = 0; kt < NKT - 2; ++kt) {
    const int sA0 = sb * 16384, sB0 = md(sb + 1) * 16384;
    const int sB1 = md(sb + 2) * 16384, sA1 = md(sb + 3) * 16384;
    // ph0: (h0,g0); stage Ah1(kt+1) -> slot sb+7
    VMC(10); PHASE_BAR();
    stageA(kt + 1, 1, md(sb + 7) * 16384);
    ldB(sB0); ldA(sA0);
    mmac(0, 0);
    // ph1: (h0,g1); stage Ah0(kt+2) -> slot sb+8
    VMC(10); PHASE_BAR();
    stageA(kt + 2, 0, md(sb + 8) * 16384);
    ldB(sB1);
    mmac(0, 1);
    // ph2: (h1,g1); stage Bg0(kt+2) -> slot sb+9
    VMC(10); PHASE_BAR();
    stageB(kt + 2, 0, md(sb + 9) * 16384);
    ldA(sA1);
    mmac(1, 1);
    // ph3: (h1,g0) re-read Bg0; stage Bg1(kt+2) -> slot sb+10
    PHASE_BAR();
    stageB(kt + 2, 1, md(sb + 10) * 16384);
    ldB(sB0);
    mmac(1, 0);
    sb = md(sb + 4);
  }
  {  // peeled tile NKT-2: stages only Ah1(NKT-1) at ph0
    const int sA0 = sb * 16384, sB0 = md(sb + 1) * 16384;
    const int sB1 = md(sb + 2) * 16384, sA1 = md(sb + 3) * 16384;
    VMC(10); PHASE_BAR();
    stageA(NKT - 1, 1, md(sb + 7) * 16384);
    ldB(sB0); ldA(sA0); mmac(0, 0);
    VMC(10); PHASE_BAR();
    ldB(sB1); mmac(0, 1);
    VMC(8); PHASE_BAR();
    ldA(sA1); mmac(1, 1);
    PHASE_BAR();
    ldB(sB0); mmac(1, 0);
    sb = md(sb + 4);
  }
  {  // peeled tile NKT-1: drain
    const int sA0 = sb * 16384, sB0 = md(sb + 1) * 16384;
    const int sB1 = md(sb + 2) * 16384, sA1 = md(sb + 3) * 16384;
    VMC(4); PHASE_BAR();
    ldB(sB0); ldA(sA0); mmac(0, 0);
    VMC(2); PHASE_BAR();
    ldB(sB1); mmac(0, 1);
    VMC(0); PHASE_BAR();
    ldA(sA1); mmac(1, 1);
    PHASE_BAR();
    ldB(sB0); mmac(1, 0);
  }
#undef PHASE_BAR
#undef VMC

  if (MODE == 0) {
    const float* tbrow = epi + bimg * 256;
    float ps[4], ps2[4];
#pragma unroll
    for (int fn = 0; fn < 4; ++fn) { ps[fn] = 0.f; ps2[fn] = 0.f; }
#pragma unroll
    for (int fm = 0; fm < 8; ++fm)
#pragma unroll
      for (int fn = 0; fn < 4; ++fn) {
        int co = wn * 64 + fn * 16 + ln;
        float add = tbrow[co];
#pragma unroll
        for (int i = 0; i < 4; ++i) {
          int m = m_base + wm * 128 + fm * 16 + (l4 << 2) + i;
          float v = acc[fm][fn][i] + add;
          h1out[(size_t)m * 256 + co] = f2bf(v);
          ps[fn] += v; ps2[fn] += v * v;
        }
      }
    // fused GN2 partial stats (channel-group g = co>>3)
#pragma unroll
    for (int fn = 0; fn < 4; ++fn) {
      float s = ps[fn], s2 = ps2[fn];
      s += __shfl_xor(s, 1);  s2 += __shfl_xor(s2, 1);
      s += __shfl_xor(s, 2);  s2 += __shfl_xor(s2, 2);
      s += __shfl_xor(s, 4);  s2 += __shfl_xor(s2, 4);
      s += __shfl_xor(s, 16); s2 += __shfl_xor(s2, 16);
      s += __shfl_xor(s, 32); s2 += __shfl_xor(s2, 32);
      if ((lane & 55) == 0) {                 // lanes 0 and 8
        int g = wn * 8 + fn * 2 + (ln >> 3);
        atomicAdd(&st2sum[bimg * 64 + g * 2 + 0], s);
        atomicAdd(&st2sum[bimg * 64 + g * 2 + 1], s2);
      }
    }
  } else {
    float* tile = (float*)lds;              // [64][257] f32
    const int pixb = m_base & 4095;
#pragma unroll
    for (int c = 0; c < 4; ++c) {
      __syncthreads();
      if (wn == c) {
#pragma unroll
        for (int fn = 0; fn < 4; ++fn) {
          int nl = fn * 16 + ln;
          int co = c * 64 + nl;
          float dsc = epi[bimg * 256 + co];
          float scb = sc_b[co];
#pragma unroll
          for (int fm = 0; fm < 8; ++fm)
#pragma unroll
            for (int i = 0; i < 4; ++i) {
              int ml = wm * 128 + fm * 16 + (l4 << 2) + i;
              tile[nl * 257 + ml] = acc[fm][fn][i] * dsc + scb;
            }
        }
      }
      __syncthreads();
#pragma unroll 4
      for (int it = 0; it < 32; ++it) {
        int lin = it * 512 + tid;
        int co_l = lin >> 8, ml = lin & 255;
        fout[((size_t)(bimg * 256 + c * 64 + co_l)) * 4096 + pixb + ml] =
            tile[co_l * 257 + ml];
      }
    }
  }
}

// ------------------------------- launch -------------------------------
extern "C" void kernel_launch(void* const* d_in, const int* in_sizes, int n_in,
                              void* d_out, int out_size, void* d_ws, size_t ws_size,
                              hipStream_t stream) {
  const float* x       = (const float*)d_in[0];
  const float* temb    = (const float*)d_in[1];
  const float* style   = (const float*)d_in[2];
  const float* gn1_g   = (const float*)d_in[3];
  const float* gn1_b   = (const float*)d_in[4];
  const float* conv1_w = (const float*)d_in[5];
  const float* conv1_b = (const float*)d_in[6];
  const float* temb_w  = (const float*)d_in[7];
  const float* temb_b  = (const float*)d_in[8];
  const float* gn2_g   = (const float*)d_in[9];
  const float* gn2_b   = (const float*)d_in[10];
  const float* style_w = (const float*)d_in[11];
  const float* style_b = (const float*)d_in[12];
  const float* mod_w   = (const float*)d_in[13];
  const float* sc_w    = (const float*)d_in[14];
  const float* sc_b    = (const float*)d_in[15];
  float* out = (float*)d_out;
  char* ws = (char*)d_ws;

  size_t o = 0;
  auto alloc = [&](size_t bytes) { size_t r = o; o += (bytes + 255) & ~(size_t)255; return r; };
  const size_t act1p_bytes = (size_t)32 * HP * WP * 128 * 2;
  const size_t xh_bytes    = (size_t)32 * 64 * 64 * 128 * 2;
  const size_t h1_bytes    = (size_t)32 * 4096 * 256 * 2;
  const size_t act2p_bytes = (size_t)32 * HP * WP * 256 * 2;
  size_t o_act1p = alloc(act1p_bytes);
  size_t o_xh    = alloc(xh_bytes);
  size_t o_h1    = alloc(h1_bytes);
  size_t o_act2p = alloc(act2p_bytes);
  size_t o_w1T   = alloc((size_t)256 * 1152 * 2);
  size_t o_wmT   = alloc((size_t)256 * 2304 * 2);
  size_t o_scTb  = alloc((size_t)32 * 256 * 128 * 2);
  size_t o_tb2   = alloc(8192 * 4);
  size_t o_mvec  = alloc(8192 * 4);
  size_t o_dvec  = alloc(8192 * 4);
  size_t o_SS    = alloc((size_t)256 * 256 * 4);
  size_t o_st1   = alloc(1024 * 8);
  size_t o_s2sum = alloc(32 * 32 * 2 * 4);
  if (ws_size < o) return;

  u16*    act1p = (u16*)(ws + o_act1p);
  u16*    xh    = (u16*)(ws + o_xh);
  u16*    h1    = (u16*)(ws + o_h1);
  u16*    act2p = (u16*)(ws + o_act2p);
  u16*    w1T   = (u16*)(ws + o_w1T);
  u16*    wmT   = (u16*)(ws + o_wmT);
  u16*    scTb  = (u16*)(ws + o_scTb);
  float*  tb2   = (float*)(ws + o_tb2);
  float*  mvec  = (float*)(ws + o_mvec);
  float*  dvec  = (float*)(ws + o_dvec);
  float*  SS_T  = (float*)(ws + o_SS);
  float2* st1   = (float2*)(ws + o_st1);
  float*  s2sum = (float*)(ws + o_s2sum);

  // zero halo borders + GN2 atomic accumulator
  halo_zero_kernel<128><<<(32 * 260 * 16 + 255) / 256, 256, 0, stream>>>(act1p);
  halo_zero_kernel<256><<<(32 * 260 * 32 + 255) / 256, 256, 0, stream>>>(act2p);
  hipMemsetAsync(s2sum, 0, 32 * 32 * 2 * 4, stream);

  repack_w_kernel<<<1152, 256, 0, stream>>>(conv1_w, w1T, 128, 1152, 256 * 1152, 9, 3);
  repack_w_kernel<<<2304, 256, 0, stream>>>(mod_w, wmT, 256, 2304, 256 * 2304, 9, 3);
  modw_ss_kernel<<<256, 256, 0, stream>>>(mod_w, SS_T);
  temb_proj_kernel<<<32, 256, 0, stream>>>(temb, temb_w, temb_b, conv1_b, tb2);
  style_mvec_kernel<<<32, 256, 0, stream>>>(style, style_w, style_b, mvec);
  demod_kernel<<<32, 256, 0, stream>>>(mvec, SS_T, dvec);
  scale_sc_kernel<<<4096, 256, 0, stream>>>(sc_w, dvec, scTb);
  gn1_stats_kernel<<<1024, 256, 0, stream>>>(x, st1);
  gn1_apply_kernel<<<2048, 256, 0, stream>>>(x, st1, gn1_g, gn1_b, act1p, xh);

  igemm_kernel<0><<<512, 512, 0, stream>>>(act1p, w1T, tb2, nullptr, nullptr,
                                           nullptr, h1, nullptr, s2sum);

  gn2_apply_kernel<<<16384, 256, 0, stream>>>(h1, s2sum, gn2_g, gn2_b, mvec, act2p);

  igemm_kernel<2><<<512, 512, 0, stream>>>(act2p, wmT, dvec, xh, scTb,
                                           sc_b, nullptr, out, nullptr);
}

// Round 11
// 405.683 us; speedup vs baseline: 1.6202x; 1.2688x over previous
//
#include <hip/hip_runtime.h>
#include <cstdint>

typedef unsigned short u16;
typedef unsigned int   u32;

typedef __attribute__((ext_vector_type(8)))  short bf16x8;
typedef __attribute__((ext_vector_type(4)))  float f32x4;
typedef __attribute__((ext_vector_type(16))) float f32x16;

#define DEV __device__ __forceinline__

static constexpr int HP = 66, WP = 66;   // padded spatial

DEV u16 f2bf(float f) {
  u32 u = __float_as_uint(f);
  u32 r = (u + 0x7fffu + ((u >> 16) & 1u)) >> 16;
  return (u16)r;
}
DEV float bf2f(u16 v) { return __uint_as_float((u32)v << 16); }

DEV void gload_lds16(const void* g, void* s) {
  __builtin_amdgcn_global_load_lds(
      (const __attribute__((address_space(1))) void*)g,
      (__attribute__((address_space(3))) void*)s, 16, 0, 0);
}

// ---------------- weight repack: OIHW fp32 -> [co][(ky*3+kx)*Cin+ci] bf16 ----------
__global__ __launch_bounds__(256) void repack_w_kernel(const float* __restrict__ src,
                                                       u16* __restrict__ dst,
                                                       int Cin, int K, int total,
                                                       int ksq, int kdim) {
  for (int idx = blockIdx.x * 256 + threadIdx.x; idx < total; idx += gridDim.x * 256) {
    int co = idx / K;
    int r  = idx - co * K;
    int s  = r / Cin;
    int ci = r - s * Cin;
    int ky = s / kdim, kx = s - ky * kdim;
    dst[idx] = f2bf(src[(co * Cin + ci) * ksq + ky * kdim + kx]);
  }
}

// ---------------- SS_T[i][o] = sum_{kh,kw} mod_w[o][i]^2 ----------------
__global__ __launch_bounds__(256) void modw_ss_kernel(const float* __restrict__ w,
                                                      float* __restrict__ SS_T) {
  int o = blockIdx.x, i = threadIdx.x;
  const float* p = w + (size_t)(o * 256 + i) * 9;
  float s = 0.f;
#pragma unroll
  for (int k = 0; k < 9; ++k) s += p[k] * p[k];
  SS_T[i * 256 + o] = s;
}

// ---------------- mvec[b][i] = style . style_w[i] + style_b[i] + 1 ----------------
__global__ __launch_bounds__(256) void style_mvec_kernel(const float* __restrict__ style,
                                                         const float* __restrict__ style_w,
                                                         const float* __restrict__ style_b,
                                                         float* __restrict__ mvec) {
  __shared__ float st[512];
  int b = blockIdx.x, t = threadIdx.x;
  for (int k = t; k < 512; k += 256) st[k] = style[b * 512 + k];
  __syncthreads();
  const float4* wr = (const float4*)(style_w + t * 512);
  float acc = 0.f;
  for (int k = 0; k < 128; ++k) {
    float4 w4 = wr[k];
    acc += w4.x * st[k*4] + w4.y * st[k*4+1] + w4.z * st[k*4+2] + w4.w * st[k*4+3];
  }
  mvec[b * 256 + t] = acc + style_b[t] + 1.f;
}

// ---------------- dvec[b][o] = rsqrt(sum_i mvec[b][i]^2 * SS_T[i][o] + eps) ---------
__global__ __launch_bounds__(256) void demod_kernel(const float* __restrict__ mvec,
                                                    const float* __restrict__ SS_T,
                                                    float* __restrict__ dvec) {
  __shared__ float m2[256];
  int b = blockIdx.x, t = threadIdx.x;
  float mv = mvec[b * 256 + t];
  m2[t] = mv * mv;
  __syncthreads();
  float acc = 0.f;
  for (int i = 0; i < 256; ++i) acc += m2[i] * SS_T[i * 256 + t];
  dvec[b * 256 + t] = rsqrtf(acc + 1e-8f);
}

// ---------------- scTb[b][co][ci] = sc_w[co][ci] / dvec[b][co]  (bf16) --------------
__global__ __launch_bounds__(256) void scale_sc_kernel(const float* __restrict__ sc_w,
                                                       const float* __restrict__ dvec,
                                                       u16* __restrict__ scTb) {
  int idx = blockIdx.x * 256 + threadIdx.x;   // 32*256*128 total
  int ci = idx & 127;
  int co = (idx >> 7) & 255;
  int b  = idx >> 15;
  scTb[idx] = f2bf(sc_w[co * 128 + ci] / dvec[b * 256 + co]);
}

// ---------------- tb2[b][co] = swish(temb[b]) . temb_w[co] + temb_b + conv1_b -------
__global__ __launch_bounds__(256) void temb_proj_kernel(const float* __restrict__ temb,
                                                        const float* __restrict__ temb_w,
                                                        const float* __restrict__ temb_b,
                                                        const float* __restrict__ conv1_b,
                                                        float* __restrict__ tb2) {
  __shared__ float sw[512];
  int b = blockIdx.x, t = threadIdx.x;
  for (int k = t; k < 512; k += 256) {
    float v = temb[b * 512 + k];
    sw[k] = v / (1.f + __expf(-v));
  }
  __syncthreads();
  const float4* wr = (const float4*)(temb_w + t * 512);
  float acc = 0.f;
  for (int k = 0; k < 128; ++k) {
    float4 w4 = wr[k];
    acc += w4.x * sw[k*4] + w4.y * sw[k*4+1] + w4.z * sw[k*4+2] + w4.w * sw[k*4+3];
  }
  tb2[b * 256 + t] = acc + temb_b[t] + conv1_b[t];
}

// ---------------- halo zero: clear only border pixels of padded NHWC buffer ---------
template <int C>
__global__ __launch_bounds__(256) void halo_zero_kernel(u16* __restrict__ buf) {
  int idx = blockIdx.x * 256 + threadIdx.x;
  const int GR = C / 8;
  if (idx >= 32 * 260 * GR) return;
  int g = idx % GR;
  int p = (idx / GR) % 260;
  int b = idx / (GR * 260);
  int y, x;
  if (p < 66)       { y = 0;        x = p; }
  else if (p < 132) { y = 65;       x = p - 66; }
  else if (p < 196) { y = p - 131;  x = 0; }
  else              { y = p - 195;  x = 65; }
  uint4 z; z.x = 0; z.y = 0; z.z = 0; z.w = 0;
  *(uint4*)(buf + (((size_t)b * HP + y) * WP + x) * C + g * 8) = z;
}

// ---------------- GN1 stats ----------------
__global__ __launch_bounds__(256) void gn1_stats_kernel(const float* __restrict__ x,
                                                        float2* __restrict__ st1) {
  int bg = blockIdx.x;
  const float4* p = (const float4*)(x + (size_t)bg * 16384);
  float s = 0.f, s2 = 0.f;
  for (int i = threadIdx.x; i < 4096; i += 256) {
    float4 v = p[i];
    s  += v.x + v.y + v.z + v.w;
    s2 += v.x*v.x + v.y*v.y + v.z*v.z + v.w*v.w;
  }
  for (int d = 32; d; d >>= 1) { s += __shfl_down(s, d); s2 += __shfl_down(s2, d); }
  __shared__ float red[2][4];
  if ((threadIdx.x & 63) == 0) { red[0][threadIdx.x >> 6] = s; red[1][threadIdx.x >> 6] = s2; }
  __syncthreads();
  if (threadIdx.x == 0) {
    s  = red[0][0] + red[0][1] + red[0][2] + red[0][3];
    s2 = red[1][0] + red[1][1] + red[1][2] + red[1][3];
    float mean = s / 16384.f;
    float var  = s2 / 16384.f - mean * mean;
    st1[bg] = make_float2(mean, rsqrtf(var + 1e-5f));
  }
}

// ---------------- GN1 apply + swish -> act1p (padded NHWC bf16); also x -> xh NHWC --
__global__ __launch_bounds__(256) void gn1_apply_kernel(const float* __restrict__ x,
                                                        const float2* __restrict__ st1,
                                                        const float* __restrict__ g1,
                                                        const float* __restrict__ b1,
                                                        u16* __restrict__ act1p,
                                                        u16* __restrict__ xh) {
  __shared__ float xs[128][65];
  int blk = blockIdx.x;
  int b = blk >> 6, y = blk & 63;
  int t = threadIdx.x;
#pragma unroll 8
  for (int pass = 0; pass < 32; ++pass) {
    int c = pass * 4 + (t >> 6);
    xs[c][t & 63] = x[(((size_t)b * 128 + c) * 64 + y) * 64 + (t & 63)];
  }
  __syncthreads();
  for (int pass = 0; pass < 32; ++pass) {
    int xc = pass * 2 + (t >> 7);
    int c  = t & 127;
    float v = xs[c][xc];
    float2 ms = st1[b * 32 + (c >> 2)];
    float vn = (v - ms.x) * ms.y * g1[c] + b1[c];
    float sw = vn / (1.f + __expf(-vn));
    act1p[(((size_t)b * HP + (y + 1)) * WP + (xc + 1)) * 128 + c] = f2bf(sw);
    xh[(((size_t)b * 64 + y) * 64 + xc) * 128 + c] = f2bf(v);
  }
}

// -- GN2 apply (stats inline from totals) + swish + in-channel mod: h1 -> act2p ------
__global__ __launch_bounds__(256) void gn2_apply_kernel(const u16* __restrict__ h1,
                                                        const float* __restrict__ st2sum,
                                                        const float* __restrict__ g2,
                                                        const float* __restrict__ b2,
                                                        const float* __restrict__ mvec,
                                                        u16* __restrict__ act2p) {
  int idx = blockIdx.x * 256 + threadIdx.x;  // granule id
  int gpix = idx >> 5;
  int gi = idx & 31;
  int c0 = gi * 8;
  int b = gpix >> 12, y = (gpix >> 6) & 63, x = gpix & 63;
  uint4 raw = *(const uint4*)(h1 + (size_t)gpix * 256 + c0);
  const u16* rs = (const u16*)&raw;
  float s  = st2sum[b * 64 + gi * 2];
  float s2 = st2sum[b * 64 + gi * 2 + 1];
  float mean = s / 32768.f;
  float rstd = rsqrtf(s2 / 32768.f - mean * mean + 1e-5f);
  const float* mv = mvec + b * 256 + c0;
  u16 outp[8];
#pragma unroll
  for (int e = 0; e < 8; ++e) {
    float v  = bf2f(rs[e]);
    float vn = (v - mean) * rstd * g2[c0 + e] + b2[c0 + e];
    float sw = vn / (1.f + __expf(-vn));
    outp[e] = f2bf(sw * mv[e]);
  }
  *(uint4*)(act2p + (((size_t)b * HP + (y + 1)) * WP + (x + 1)) * 256 + c0) = *(const uint4*)outp;
}

// ---------- implicit-GEMM conv: 256x256 tile, 8 waves, BK=64, 4-phase schedule ------
// Round-7 sync skeleton (stage -> vmcnt(6) -> barrier -> ds_read -> MFMA), with
// v_mfma_f32_32x32x16_bf16: 32 MFMA/wave/K-tile (vs 64), fragment registers
// retained across phases (af for h, bf0 for ph3) -> 20 ds_read_b128/K-tile.
// A frag: row = wm*64+rb2*32+(l&31) (in half h), granule (ks*2+(l>>5))^(l&7).
// C/D: col = lane&31, row = (i&3)+8*(i>>2)+4*(lane>>5)  [guide m74/m101].
// MODE 0: conv1 -> h1 bf16 NHWC + fused GN2 partial stats (atomics).
// MODE 2: modconv + fused 1x1 shortcut -> d_out NCHW fp32 = acc*dvec + sc_b.
template <int MODE>
__global__ __launch_bounds__(512, 2) void igemm_kernel(const u16* __restrict__ act,
                                                       const u16* __restrict__ wT,
                                                       const float* __restrict__ epi,
                                                       const u16* __restrict__ xh,
                                                       const u16* __restrict__ scTb,
                                                       const float* __restrict__ sc_b,
                                                       u16* __restrict__ h1out,
                                                       float* __restrict__ fout,
                                                       float* __restrict__ st2sum) {
  constexpr int CIN    = (MODE == 0) ? 128 : 256;
  constexpr int NSUB   = CIN / 64;
  constexpr int KW     = CIN * 9;
  constexpr int NKMAIN = KW / 64;                 // 18 / 36
  constexpr int NKT    = (MODE == 2) ? NKMAIN + 2 : NKMAIN;

  __shared__ __align__(16) unsigned char lds[131072];
  const int tid  = threadIdx.x;
  const int wave = tid >> 6, lane = tid & 63;
  const int wm = wave >> 2, wn = wave & 3;        // 2 x 4 waves
  const int m_base = blockIdx.x * 256;
  const int bimg = m_base >> 12;
  const int l31 = lane & 31, l5 = lane >> 5;

  // staging lane constants (identical mapping to round 7)
  const int srow = lane >> 3;                     // 0..7
  const int glog = (lane & 7) ^ srow;             // pre-swizzled source granule

  u32 pixA[2][2], pixX[2][2], rowB[2][2], rowS[2][2];
#pragma unroll
  for (int j = 0; j < 2; ++j)
#pragma unroll
    for (int h = 0; h < 2; ++h) {
      int mlocal = (wave & 3) * 16 + j * 8 + srow + h * 64 + (wave >> 2) * 128;
      int m = m_base + mlocal;
      int y = (m >> 6) & 63, x = m & 63;
      pixA[j][h] = (u32)((bimg * HP + y) * WP + x) * CIN + glog * 8;
      if (MODE == 2) pixX[j][h] = (u32)m * 128 + glog * 8;
      int co = (wave >> 1) * 64 + h * 32 + (wave & 1) * 16 + j * 8 + srow;
      rowB[j][h] = (u32)co * KW + glog * 8;
      if (MODE == 2) rowS[j][h] = (u32)(bimg * 256 + co) * 128 + glog * 8;
    }

  f32x16 acc32[4][2];
#pragma unroll
  for (int i = 0; i < 4; ++i)
#pragma unroll
    for (int j = 0; j < 2; ++j)
#pragma unroll
      for (int e = 0; e < 16; ++e) acc32[i][j][e] = 0.f;

  auto stageA = [&](int kt, int h, int buf) {
    unsigned char* dst = lds + buf * 65536 + h * 16384 + wave * 2048;
    if (MODE == 2 && kt >= NKMAIN) {
      u32 ko = (u32)(kt - NKMAIN) * 64;
      gload_lds16(xh + pixX[0][h] + ko, dst);
      gload_lds16(xh + pixX[1][h] + ko, dst + 1024);
    } else {
      int tap = kt / NSUB;
      int kin = (kt - tap * NSUB) * 64;
      int ky = tap / 3, kx = tap - ky * 3;
      u32 ko = (u32)((ky * WP + kx) * CIN + kin);
      gload_lds16(act + pixA[0][h] + ko, dst);
      gload_lds16(act + pixA[1][h] + ko, dst + 1024);
    }
  };
  auto stageB = [&](int kt, int g, int buf) {
    unsigned char* dst = lds + buf * 65536 + 32768 + g * 16384 + wave * 2048;
    if (MODE == 2 && kt >= NKMAIN) {
      u32 ko = (u32)(kt - NKMAIN) * 64;
      gload_lds16(scTb + rowS[0][g] + ko, dst);
      gload_lds16(scTb + rowS[1][g] + ko, dst + 1024);
    } else {
      u32 ko = (u32)kt * 64;
      gload_lds16(wT + rowB[0][g] + ko, dst);
      gload_lds16(wT + rowB[1][g] + ko, dst + 1024);
    }
  };

  bf16x8 af[8], bf0[4], bf1[4];     // af: [rb2*4+ks] for current h
  auto ldA32 = [&](int h, int buf) {
    const unsigned char* As = lds + buf * 65536 + h * 16384;
#pragma unroll
    for (int rb2 = 0; rb2 < 2; ++rb2)
#pragma unroll
      for (int ks = 0; ks < 4; ++ks) {
        int row = wm * 64 + rb2 * 32 + l31;
        int gr  = (ks * 2 + l5) ^ (lane & 7);
        af[rb2 * 4 + ks] = *(const bf16x8*)(As + row * 128 + gr * 16);
      }
  };
  auto ldB32 = [&](int g, int buf, bf16x8* bfr) {
    const unsigned char* Bs = lds + buf * 65536 + 32768 + g * 16384;
    int row = wn * 32 + l31;
#pragma unroll
    for (int ks = 0; ks < 4; ++ks) {
      int gr = (ks * 2 + l5) ^ (lane & 7);
      bfr[ks] = *(const bf16x8*)(Bs + row * 128 + gr * 16);
    }
  };
  auto mmac32 = [&](int h, int g, bf16x8* bfr) {
    __builtin_amdgcn_s_setprio(1);
#pragma unroll
    for (int rb2 = 0; rb2 < 2; ++rb2)
#pragma unroll
      for (int ks = 0; ks < 4; ++ks)
        acc32[h * 2 + rb2][g] = __builtin_amdgcn_mfma_f32_32x32x16_bf16(
            af[rb2 * 4 + ks], bfr[ks], acc32[h * 2 + rb2][g], 0, 0, 0);
    __builtin_amdgcn_s_setprio(0);
  };

#define PHASE_BAR() do { __builtin_amdgcn_sched_barrier(0); \
    __builtin_amdgcn_s_barrier(); __builtin_amdgcn_sched_barrier(0); } while (0)

  // prologue: tile 0 -> buf0, in consumption order Ah0, Bg0, Bg1, Ah1
  stageA(0, 0, 0); stageB(0, 0, 0); stageB(0, 1, 0); stageA(0, 1, 0);

#pragma unroll 2
  for (int kt = 0; kt < NKT - 1; ++kt) {
    const int cur = kt & 1, nxt = cur ^ 1;
    // ph0: (h0,g0)
    stageA(kt + 1, 0, nxt);
    asm volatile("s_waitcnt vmcnt(6)" ::: "memory");
    PHASE_BAR();
    ldB32(0, cur, bf0); ldA32(0, cur);
    mmac32(0, 0, bf0);
    // ph1: (h0,g1)  (af reused)
    stageB(kt + 1, 0, nxt);
    asm volatile("s_waitcnt vmcnt(6)" ::: "memory");
    PHASE_BAR();
    ldB32(1, cur, bf1);
    mmac32(0, 1, bf1);
    // ph2: (h1,g1)  (bf1 reused)
    stageB(kt + 1, 1, nxt);
    asm volatile("s_waitcnt vmcnt(6)" ::: "memory");
    PHASE_BAR();
    ldA32(1, cur);
    mmac32(1, 1, bf1);
    // ph3: (h1,g0)  (af + bf0 reused, no ds_read)
    stageA(kt + 1, 1, nxt);
    PHASE_BAR();
    mmac32(1, 0, bf0);
  }
  {  // last tile (no staging): drain progressively
    const int cur = (NKT - 1) & 1;
    asm volatile("s_waitcnt vmcnt(4)" ::: "memory");
    PHASE_BAR();
    ldB32(0, cur, bf0); ldA32(0, cur); mmac32(0, 0, bf0);
    asm volatile("s_waitcnt vmcnt(2)" ::: "memory");
    PHASE_BAR();
    ldB32(1, cur, bf1); mmac32(0, 1, bf1);
    asm volatile("s_waitcnt vmcnt(0)" ::: "memory");
    PHASE_BAR();
    ldA32(1, cur); mmac32(1, 1, bf1);
    PHASE_BAR();
    mmac32(1, 0, bf0);
  }
#undef PHASE_BAR

  if (MODE == 0) {
    const float* tbrow = epi + bimg * 256;
    float ps[2], ps2[2];
#pragma unroll
    for (int cb = 0; cb < 2; ++cb) { ps[cb] = 0.f; ps2[cb] = 0.f; }
#pragma unroll
    for (int rb = 0; rb < 4; ++rb)
#pragma unroll
      for (int cb = 0; cb < 2; ++cb) {
        int co = wn * 64 + cb * 32 + l31;
        float add = tbrow[co];
#pragma unroll
        for (int i = 0; i < 16; ++i) {
          int row = (i & 3) + 8 * (i >> 2) + 4 * l5;
          int m = m_base + wm * 128 + rb * 32 + row;
          float v = acc32[rb][cb][i] + add;
          h1out[(size_t)m * 256 + co] = f2bf(v);
          ps[cb] += v; ps2[cb] += v * v;
        }
      }
    // fused GN2 partial stats (channel-group g = co>>3)
#pragma unroll
    for (int cb = 0; cb < 2; ++cb) {
      float s = ps[cb], s2 = ps2[cb];
      s += __shfl_xor(s, 1);  s2 += __shfl_xor(s2, 1);
      s += __shfl_xor(s, 2);  s2 += __shfl_xor(s2, 2);
      s += __shfl_xor(s, 4);  s2 += __shfl_xor(s2, 4);
      s += __shfl_xor(s, 32); s2 += __shfl_xor(s2, 32);
      if ((lane & 39) == 0) {               // lanes 0,8,16,24
        int g = wn * 8 + cb * 4 + (l31 >> 3);
        atomicAdd(&st2sum[bimg * 64 + g * 2 + 0], s);
        atomicAdd(&st2sum[bimg * 64 + g * 2 + 1], s2);
      }
    }
  } else {
    float* tile = (float*)lds;              // [64][257] f32
    const int pixb = m_base & 4095;
#pragma unroll
    for (int c = 0; c < 4; ++c) {
      __syncthreads();
      if (wn == c) {
#pragma unroll
        for (int cb = 0; cb < 2; ++cb) {
          int nl = cb * 32 + l31;
          int co = c * 64 + nl;
          float dsc = epi[bimg * 256 + co];
          float scb = sc_b[co];
#pragma unroll
          for (int rb = 0; rb < 4; ++rb)
#pragma unroll
            for (int i = 0; i < 16; ++i) {
              int ml = wm * 128 + rb * 32 + (i & 3) + 8 * (i >> 2) + 4 * l5;
              tile[nl * 257 + ml] = acc32[rb][cb][i] * dsc + scb;
            }
        }
      }
      __syncthreads();
#pragma unroll 4
      for (int it = 0; it < 32; ++it) {
        int lin = it * 512 + tid;
        int co_l = lin >> 8, ml = lin & 255;
        fout[((size_t)(bimg * 256 + c * 64 + co_l)) * 4096 + pixb + ml] =
            tile[co_l * 257 + ml];
      }
    }
  }
}

// ------------------------------- launch -------------------------------
extern "C" void kernel_launch(void* const* d_in, const int* in_sizes, int n_in,
                              void* d_out, int out_size, void* d_ws, size_t ws_size,
                              hipStream_t stream) {
  const float* x       = (const float*)d_in[0];
  const float* temb    = (const float*)d_in[1];
  const float* style   = (const float*)d_in[2];
  const float* gn1_g   = (const float*)d_in[3];
  const float* gn1_b   = (const float*)d_in[4];
  const float* conv1_w = (const float*)d_in[5];
  const float* conv1_b = (const float*)d_in[6];
  const float* temb_w  = (const float*)d_in[7];
  const float* temb_b  = (const float*)d_in[8];
  const float* gn2_g   = (const float*)d_in[9];
  const float* gn2_b   = (const float*)d_in[10];
  const float* style_w = (const float*)d_in[11];
  const float* style_b = (const float*)d_in[12];
  const float* mod_w   = (const float*)d_in[13];
  const float* sc_w    = (const float*)d_in[14];
  const float* sc_b    = (const float*)d_in[15];
  float* out = (float*)d_out;
  char* ws = (char*)d_ws;

  size_t o = 0;
  auto alloc = [&](size_t bytes) { size_t r = o; o += (bytes + 255) & ~(size_t)255; return r; };
  const size_t act1p_bytes = (size_t)32 * HP * WP * 128 * 2;
  const size_t xh_bytes    = (size_t)32 * 64 * 64 * 128 * 2;
  const size_t h1_bytes    = (size_t)32 * 4096 * 256 * 2;
  const size_t act2p_bytes = (size_t)32 * HP * WP * 256 * 2;
  size_t o_act1p = alloc(act1p_bytes);
  size_t o_xh    = alloc(xh_bytes);
  size_t o_h1    = alloc(h1_bytes);
  size_t o_act2p = alloc(act2p_bytes);
  size_t o_w1T   = alloc((size_t)256 * 1152 * 2);
  size_t o_wmT   = alloc((size_t)256 * 2304 * 2);
  size_t o_scTb  = alloc((size_t)32 * 256 * 128 * 2);
  size_t o_tb2   = alloc(8192 * 4);
  size_t o_mvec  = alloc(8192 * 4);
  size_t o_dvec  = alloc(8192 * 4);
  size_t o_SS    = alloc((size_t)256 * 256 * 4);
  size_t o_st1   = alloc(1024 * 8);
  size_t o_s2sum = alloc(32 * 32 * 2 * 4);
  if (ws_size < o) return;

  u16*    act1p = (u16*)(ws + o_act1p);
  u16*    xh    = (u16*)(ws + o_xh);
  u16*    h1    = (u16*)(ws + o_h1);
  u16*    act2p = (u16*)(ws + o_act2p);
  u16*    w1T   = (u16*)(ws + o_w1T);
  u16*    wmT   = (u16*)(ws + o_wmT);
  u16*    scTb  = (u16*)(ws + o_scTb);
  float*  tb2   = (float*)(ws + o_tb2);
  float*  mvec  = (float*)(ws + o_mvec);
  float*  dvec  = (float*)(ws + o_dvec);
  float*  SS_T  = (float*)(ws + o_SS);
  float2* st1   = (float2*)(ws + o_st1);
  float*  s2sum = (float*)(ws + o_s2sum);

  // zero halo borders + GN2 atomic accumulator
  halo_zero_kernel<128><<<(32 * 260 * 16 + 255) / 256, 256, 0, stream>>>(act1p);
  halo_zero_kernel<256><<<(32 * 260 * 32 + 255) / 256, 256, 0, stream>>>(act2p);
  hipMemsetAsync(s2sum, 0, 32 * 32 * 2 * 4, stream);

  repack_w_kernel<<<1152, 256, 0, stream>>>(conv1_w, w1T, 128, 1152, 256 * 1152, 9, 3);
  repack_w_kernel<<<2304, 256, 0, stream>>>(mod_w, wmT, 256, 2304, 256 * 2304, 9, 3);
  modw_ss_kernel<<<256, 256, 0, stream>>>(mod_w, SS_T);
  temb_proj_kernel<<<32, 256, 0, stream>>>(temb, temb_w, temb_b, conv1_b, tb2);
  style_mvec_kernel<<<32, 256, 0, stream>>>(style, style_w, style_b, mvec);
  demod_kernel<<<32, 256, 0, stream>>>(mvec, SS_T, dvec);
  scale_sc_kernel<<<4096, 256, 0, stream>>>(sc_w, dvec, scTb);
  gn1_stats_kernel<<<1024, 256, 0, stream>>>(x, st1);
  gn1_apply_kernel<<<2048, 256, 0, stream>>>(x, st1, gn1_g, gn1_b, act1p, xh);

  igemm_kernel<0><<<512, 512, 0, stream>>>(act1p, w1T, tb2, nullptr, nullptr,
                                           nullptr, h1, nullptr, s2sum);

  gn2_apply_kernel<<<16384, 256, 0, stream>>>(h1, s2sum, gn2_g, gn2_b, mvec, act2p);

  igemm_kernel<2><<<512, 512, 0, stream>>>(act2p, wmT, dvec, xh, scTb,
                                           sc_b, nullptr, out, nullptr);
}

// Round 12
// 376.545 us; speedup vs baseline: 1.7455x; 1.0774x over previous
//
#include <hip/hip_runtime.h>
#include <cstdint>

typedef unsigned short u16;
typedef unsigned int   u32;

typedef __attribute__((ext_vector_type(8))) short bf16x8;
typedef __attribute__((ext_vector_type(4))) float f32x4;

#define DEV __device__ __forceinline__

static constexpr int HP = 66, WP = 66;   // padded spatial

DEV u16 f2bf(float f) {
  u32 u = __float_as_uint(f);
  u32 r = (u + 0x7fffu + ((u >> 16) & 1u)) >> 16;
  return (u16)r;
}
DEV float bf2f(u16 v) { return __uint_as_float((u32)v << 16); }

DEV void gload_lds16(const void* g, void* s) {
  __builtin_amdgcn_global_load_lds(
      (const __attribute__((address_space(1))) void*)g,
      (__attribute__((address_space(3))) void*)s, 16, 0, 0);
}

// ---------------- weight repack: OIHW fp32 -> [co][(ky*3+kx)*Cin+ci] bf16 ----------
__global__ __launch_bounds__(256) void repack_w_kernel(const float* __restrict__ src,
                                                       u16* __restrict__ dst,
                                                       int Cin, int K, int total,
                                                       int ksq, int kdim) {
  for (int idx = blockIdx.x * 256 + threadIdx.x; idx < total; idx += gridDim.x * 256) {
    int co = idx / K;
    int r  = idx - co * K;
    int s  = r / Cin;
    int ci = r - s * Cin;
    int ky = s / kdim, kx = s - ky * kdim;
    dst[idx] = f2bf(src[(co * Cin + ci) * ksq + ky * kdim + kx]);
  }
}

// ---------------- SS_T[i][o] = sum_{kh,kw} mod_w[o][i]^2 ----------------
__global__ __launch_bounds__(256) void modw_ss_kernel(const float* __restrict__ w,
                                                      float* __restrict__ SS_T) {
  int o = blockIdx.x, i = threadIdx.x;
  const float* p = w + (size_t)(o * 256 + i) * 9;
  float s = 0.f;
#pragma unroll
  for (int k = 0; k < 9; ++k) s += p[k] * p[k];
  SS_T[i * 256 + o] = s;
}

// ---------------- mvec[b][i] = style . style_w[i] + style_b[i] + 1 ----------------
__global__ __launch_bounds__(256) void style_mvec_kernel(const float* __restrict__ style,
                                                         const float* __restrict__ style_w,
                                                         const float* __restrict__ style_b,
                                                         float* __restrict__ mvec) {
  __shared__ float st[512];
  int b = blockIdx.x, t = threadIdx.x;
  for (int k = t; k < 512; k += 256) st[k] = style[b * 512 + k];
  __syncthreads();
  const float4* wr = (const float4*)(style_w + t * 512);
  float acc = 0.f;
  for (int k = 0; k < 128; ++k) {
    float4 w4 = wr[k];
    acc += w4.x * st[k*4] + w4.y * st[k*4+1] + w4.z * st[k*4+2] + w4.w * st[k*4+3];
  }
  mvec[b * 256 + t] = acc + style_b[t] + 1.f;
}

// ---------------- dvec[b][o] = rsqrt(sum_i mvec[b][i]^2 * SS_T[i][o] + eps) ---------
__global__ __launch_bounds__(256) void demod_kernel(const float* __restrict__ mvec,
                                                    const float* __restrict__ SS_T,
                                                    float* __restrict__ dvec) {
  __shared__ float m2[256];
  int b = blockIdx.x, t = threadIdx.x;
  float mv = mvec[b * 256 + t];
  m2[t] = mv * mv;
  __syncthreads();
  float acc = 0.f;
  for (int i = 0; i < 256; ++i) acc += m2[i] * SS_T[i * 256 + t];
  dvec[b * 256 + t] = rsqrtf(acc + 1e-8f);
}

// ---------------- scTb[b][co][ci] = sc_w[co][ci] / dvec[b][co]  (bf16) --------------
__global__ __launch_bounds__(256) void scale_sc_kernel(const float* __restrict__ sc_w,
                                                       const float* __restrict__ dvec,
                                                       u16* __restrict__ scTb) {
  int idx = blockIdx.x * 256 + threadIdx.x;   // 32*256*128 total
  int ci = idx & 127;
  int co = (idx >> 7) & 255;
  int b  = idx >> 15;
  scTb[idx] = f2bf(sc_w[co * 128 + ci] / dvec[b * 256 + co]);
}

// ---------------- tb2[b][co] = swish(temb[b]) . temb_w[co] + temb_b + conv1_b -------
__global__ __launch_bounds__(256) void temb_proj_kernel(const float* __restrict__ temb,
                                                        const float* __restrict__ temb_w,
                                                        const float* __restrict__ temb_b,
                                                        const float* __restrict__ conv1_b,
                                                        float* __restrict__ tb2) {
  __shared__ float sw[512];
  int b = blockIdx.x, t = threadIdx.x;
  for (int k = t; k < 512; k += 256) {
    float v = temb[b * 512 + k];
    sw[k] = v / (1.f + __expf(-v));
  }
  __syncthreads();
  const float4* wr = (const float4*)(temb_w + t * 512);
  float acc = 0.f;
  for (int k = 0; k < 128; ++k) {
    float4 w4 = wr[k];
    acc += w4.x * sw[k*4] + w4.y * sw[k*4+1] + w4.z * sw[k*4+2] + w4.w * sw[k*4+3];
  }
  tb2[b * 256 + t] = acc + temb_b[t] + conv1_b[t];
}

// ---------------- halo zero: clear only border pixels of padded NHWC buffer ---------
template <int C>
__global__ __launch_bounds__(256) void halo_zero_kernel(u16* __restrict__ buf) {
  int idx = blockIdx.x * 256 + threadIdx.x;
  const int GR = C / 8;
  if (idx >= 32 * 260 * GR) return;
  int g = idx % GR;
  int p = (idx / GR) % 260;
  int b = idx / (GR * 260);
  int y, x;
  if (p < 66)       { y = 0;        x = p; }
  else if (p < 132) { y = 65;       x = p - 66; }
  else if (p < 196) { y = p - 131;  x = 0; }
  else              { y = p - 195;  x = 65; }
  uint4 z; z.x = 0; z.y = 0; z.z = 0; z.w = 0;
  *(uint4*)(buf + (((size_t)b * HP + y) * WP + x) * C + g * 8) = z;
}

// ---------------- GN1 stats ----------------
__global__ __launch_bounds__(256) void gn1_stats_kernel(const float* __restrict__ x,
                                                        float2* __restrict__ st1) {
  int bg = blockIdx.x;
  const float4* p = (const float4*)(x + (size_t)bg * 16384);
  float s = 0.f, s2 = 0.f;
  for (int i = threadIdx.x; i < 4096; i += 256) {
    float4 v = p[i];
    s  += v.x + v.y + v.z + v.w;
    s2 += v.x*v.x + v.y*v.y + v.z*v.z + v.w*v.w;
  }
  for (int d = 32; d; d >>= 1) { s += __shfl_down(s, d); s2 += __shfl_down(s2, d); }
  __shared__ float red[2][4];
  if ((threadIdx.x & 63) == 0) { red[0][threadIdx.x >> 6] = s; red[1][threadIdx.x >> 6] = s2; }
  __syncthreads();
  if (threadIdx.x == 0) {
    s  = red[0][0] + red[0][1] + red[0][2] + red[0][3];
    s2 = red[1][0] + red[1][1] + red[1][2] + red[1][3];
    float mean = s / 16384.f;
    float var  = s2 / 16384.f - mean * mean;
    st1[bg] = make_float2(mean, rsqrtf(var + 1e-5f));
  }
}

// ---------------- GN1 apply + swish -> act1p (padded NHWC bf16); also x -> xh NHWC --
__global__ __launch_bounds__(256) void gn1_apply_kernel(const float* __restrict__ x,
                                                        const float2* __restrict__ st1,
                                                        const float* __restrict__ g1,
                                                        const float* __restrict__ b1,
                                                        u16* __restrict__ act1p,
                                                        u16* __restrict__ xh) {
  __shared__ float xs[128][65];
  int blk = blockIdx.x;
  int b = blk >> 6, y = blk & 63;
  int t = threadIdx.x;
#pragma unroll 8
  for (int pass = 0; pass < 32; ++pass) {
    int c = pass * 4 + (t >> 6);
    xs[c][t & 63] = x[(((size_t)b * 128 + c) * 64 + y) * 64 + (t & 63)];
  }
  __syncthreads();
  for (int pass = 0; pass < 32; ++pass) {
    int xc = pass * 2 + (t >> 7);
    int c  = t & 127;
    float v = xs[c][xc];
    float2 ms = st1[b * 32 + (c >> 2)];
    float vn = (v - ms.x) * ms.y * g1[c] + b1[c];
    float sw = vn / (1.f + __expf(-vn));
    act1p[(((size_t)b * HP + (y + 1)) * WP + (xc + 1)) * 128 + c] = f2bf(sw);
    xh[(((size_t)b * 64 + y) * 64 + xc) * 128 + c] = f2bf(v);
  }
}

// -- GN2 apply (stats inline from totals) + swish + in-channel mod: h1 -> act2p ------
__global__ __launch_bounds__(256) void gn2_apply_kernel(const u16* __restrict__ h1,
                                                        const float* __restrict__ st2sum,
                                                        const float* __restrict__ g2,
                                                        const float* __restrict__ b2,
                                                        const float* __restrict__ mvec,
                                                        u16* __restrict__ act2p) {
  int idx = blockIdx.x * 256 + threadIdx.x;  // granule id
  int gpix = idx >> 5;
  int gi = idx & 31;
  int c0 = gi * 8;
  int b = gpix >> 12, y = (gpix >> 6) & 63, x = gpix & 63;
  uint4 raw = *(const uint4*)(h1 + (size_t)gpix * 256 + c0);
  const u16* rs = (const u16*)&raw;
  float s  = st2sum[b * 64 + gi * 2];
  float s2 = st2sum[b * 64 + gi * 2 + 1];
  float mean = s / 32768.f;
  float rstd = rsqrtf(s2 / 32768.f - mean * mean + 1e-5f);
  const float* mv = mvec + b * 256 + c0;
  u16 outp[8];
#pragma unroll
  for (int e = 0; e < 8; ++e) {
    float v  = bf2f(rs[e]);
    float vn = (v - mean) * rstd * g2[c0 + e] + b2[c0 + e];
    float sw = vn / (1.f + __expf(-vn));
    outp[e] = f2bf(sw * mv[e]);
  }
  *(uint4*)(act2p + (((size_t)b * HP + (y + 1)) * WP + (x + 1)) * 256 + c0) = *(const uint4*)outp;
}

// ---------- implicit-GEMM conv: 256x256 tile, 8 waves, BK=64, 4-phase schedule ------
// Round-7 proven schedule (stage -> vmcnt(6) -> barrier -> ds_read -> MFMA), plus
// register retention: bf0 kept live ph0->ph3 (ph3 has ZERO ds_reads), af kept
// across the two g-phases of each half. 24 ds_read_b128/wave/K-tile (was 28).
// MODE 0: conv1 -> h1 bf16 NHWC + fused GN2 partial stats (atomics).
// MODE 2: modconv + fused 1x1 shortcut -> d_out NCHW fp32 = acc*dvec + sc_b.
template <int MODE>
__global__ __launch_bounds__(512, 2) void igemm_kernel(const u16* __restrict__ act,
                                                       const u16* __restrict__ wT,
                                                       const float* __restrict__ epi,
                                                       const u16* __restrict__ xh,
                                                       const u16* __restrict__ scTb,
                                                       const float* __restrict__ sc_b,
                                                       u16* __restrict__ h1out,
                                                       float* __restrict__ fout,
                                                       float* __restrict__ st2sum) {
  constexpr int CIN    = (MODE == 0) ? 128 : 256;
  constexpr int NSUB   = CIN / 64;
  constexpr int KW     = CIN * 9;
  constexpr int NKMAIN = KW / 64;                 // 18 / 36
  constexpr int NKT    = (MODE == 2) ? NKMAIN + 2 : NKMAIN;

  __shared__ __align__(16) unsigned char lds[131072];
  const int tid  = threadIdx.x;
  const int wave = tid >> 6, lane = tid & 63;
  const int wm = wave >> 2, wn = wave & 3;        // 2 x 4 waves
  const int m_base = blockIdx.x * 256;
  const int bimg = m_base >> 12;
  const int ln = lane & 15, l4 = lane >> 4;

  // staging lane constants (identical mapping to round 7)
  const int srow = lane >> 3;                     // 0..7
  const int glog = (lane & 7) ^ srow;             // pre-swizzled source granule

  u32 pixA[2][2], pixX[2][2], rowB[2][2], rowS[2][2];
#pragma unroll
  for (int j = 0; j < 2; ++j)
#pragma unroll
    for (int h = 0; h < 2; ++h) {
      int mlocal = (wave & 3) * 16 + j * 8 + srow + h * 64 + (wave >> 2) * 128;
      int m = m_base + mlocal;
      int y = (m >> 6) & 63, x = m & 63;
      pixA[j][h] = (u32)((bimg * HP + y) * WP + x) * CIN + glog * 8;
      if (MODE == 2) pixX[j][h] = (u32)m * 128 + glog * 8;
      int co = (wave >> 1) * 64 + h * 32 + (wave & 1) * 16 + j * 8 + srow;
      rowB[j][h] = (u32)co * KW + glog * 8;
      if (MODE == 2) rowS[j][h] = (u32)(bimg * 256 + co) * 128 + glog * 8;
    }

  f32x4 acc[8][4];
#pragma unroll
  for (int i = 0; i < 8; ++i)
#pragma unroll
    for (int j = 0; j < 4; ++j) acc[i][j] = (f32x4){0.f, 0.f, 0.f, 0.f};

  auto stageA = [&](int kt, int h, int buf) {
    unsigned char* dst = lds + buf * 65536 + h * 16384 + wave * 2048;
    if (MODE == 2 && kt >= NKMAIN) {
      u32 ko = (u32)(kt - NKMAIN) * 64;
      gload_lds16(xh + pixX[0][h] + ko, dst);
      gload_lds16(xh + pixX[1][h] + ko, dst + 1024);
    } else {
      int tap = kt / NSUB;
      int kin = (kt - tap * NSUB) * 64;
      int ky = tap / 3, kx = tap - ky * 3;
      u32 ko = (u32)((ky * WP + kx) * CIN + kin);
      gload_lds16(act + pixA[0][h] + ko, dst);
      gload_lds16(act + pixA[1][h] + ko, dst + 1024);
    }
  };
  auto stageB = [&](int kt, int g, int buf) {
    unsigned char* dst = lds + buf * 65536 + 32768 + g * 16384 + wave * 2048;
    if (MODE == 2 && kt >= NKMAIN) {
      u32 ko = (u32)(kt - NKMAIN) * 64;
      gload_lds16(scTb + rowS[0][g] + ko, dst);
      gload_lds16(scTb + rowS[1][g] + ko, dst + 1024);
    } else {
      u32 ko = (u32)kt * 64;
      gload_lds16(wT + rowB[0][g] + ko, dst);
      gload_lds16(wT + rowB[1][g] + ko, dst + 1024);
    }
  };

  bf16x8 af[8], bf0[4], bf1[4];
  auto ldA = [&](int h, int buf) {
    const unsigned char* As = lds + buf * 65536;
#pragma unroll
    for (int f = 0; f < 4; ++f)
#pragma unroll
      for (int kk = 0; kk < 2; ++kk) {
        int lr = h * 128 + wm * 64 + f * 16 + ln;
        int gr = (kk * 4 + l4) ^ (lr & 7);
        af[f * 2 + kk] = *(const bf16x8*)(As + lr * 128 + gr * 16);
      }
  };
  auto ldB = [&](int g, int buf, bf16x8* bfr) {
    const unsigned char* Bs = lds + buf * 65536 + 32768;
#pragma unroll
    for (int f1 = 0; f1 < 2; ++f1)
#pragma unroll
      for (int kk = 0; kk < 2; ++kk) {
        int lr = g * 128 + wn * 32 + f1 * 16 + ln;
        int gr = (kk * 4 + l4) ^ (lr & 7);
        bfr[f1 * 2 + kk] = *(const bf16x8*)(Bs + lr * 128 + gr * 16);
      }
  };
  auto mmac = [&](int h, int g, const bf16x8* bfr) {
    __builtin_amdgcn_s_setprio(1);
#pragma unroll
    for (int f = 0; f < 4; ++f)
#pragma unroll
      for (int f1 = 0; f1 < 2; ++f1)
#pragma unroll
        for (int kk = 0; kk < 2; ++kk)
          acc[h * 4 + f][g * 2 + f1] = __builtin_amdgcn_mfma_f32_16x16x32_bf16(
              af[f * 2 + kk], bfr[f1 * 2 + kk], acc[h * 4 + f][g * 2 + f1], 0, 0, 0);
    __builtin_amdgcn_s_setprio(0);
  };

#define PHASE_BAR() do { __builtin_amdgcn_sched_barrier(0); \
    __builtin_amdgcn_s_barrier(); __builtin_amdgcn_sched_barrier(0); } while (0)

  // prologue: tile 0 -> buf0, in consumption order Ah0, Bg0, Bg1, Ah1
  stageA(0, 0, 0); stageB(0, 0, 0); stageB(0, 1, 0); stageA(0, 1, 0);

#pragma unroll 2
  for (int kt = 0; kt < NKT - 1; ++kt) {
    const int cur = kt & 1, nxt = cur ^ 1;
    // ph0: (h0,g0)
    stageA(kt + 1, 0, nxt);
    asm volatile("s_waitcnt vmcnt(6)" ::: "memory");
    PHASE_BAR();
    ldB(0, cur, bf0); ldA(0, cur);
    mmac(0, 0, bf0);
    // ph1: (h0,g1)  (af reused)
    stageB(kt + 1, 0, nxt);
    asm volatile("s_waitcnt vmcnt(6)" ::: "memory");
    PHASE_BAR();
    ldB(1, cur, bf1);
    mmac(0, 1, bf1);
    // ph2: (h1,g1)  (bf1 reused)
    stageB(kt + 1, 1, nxt);
    asm volatile("s_waitcnt vmcnt(6)" ::: "memory");
    PHASE_BAR();
    ldA(1, cur);
    mmac(1, 1, bf1);
    // ph3: (h1,g0)  (af + bf0 reused -> NO ds_reads)
    stageA(kt + 1, 1, nxt);
    PHASE_BAR();
    mmac(1, 0, bf0);
  }
  {  // last tile (no staging): drain progressively
    const int cur = (NKT - 1) & 1;
    asm volatile("s_waitcnt vmcnt(4)" ::: "memory");
    PHASE_BAR();
    ldB(0, cur, bf0); ldA(0, cur); mmac(0, 0, bf0);
    asm volatile("s_waitcnt vmcnt(2)" ::: "memory");
    PHASE_BAR();
    ldB(1, cur, bf1); mmac(0, 1, bf1);
    asm volatile("s_waitcnt vmcnt(0)" ::: "memory");
    PHASE_BAR();
    ldA(1, cur); mmac(1, 1, bf1);
    PHASE_BAR();
    mmac(1, 0, bf0);
  }
#undef PHASE_BAR

  if (MODE == 0) {
    const float* tbrow = epi + bimg * 256;
    float ps[4], ps2[4];
#pragma unroll
    for (int fn = 0; fn < 4; ++fn) { ps[fn] = 0.f; ps2[fn] = 0.f; }
#pragma unroll
    for (int fm = 0; fm < 8; ++fm)
#pragma unroll
      for (int fn = 0; fn < 4; ++fn) {
        int co = wn * 64 + fn * 16 + ln;
        float add = tbrow[co];
#pragma unroll
        for (int i = 0; i < 4; ++i) {
          int m = m_base + wm * 128 + fm * 16 + (l4 << 2) + i;
          float v = acc[fm][fn][i] + add;
          h1out[(size_t)m * 256 + co] = f2bf(v);
          ps[fn] += v; ps2[fn] += v * v;
        }
      }
    // fused GN2 partial stats (channel-group g = co>>3)
#pragma unroll
    for (int fn = 0; fn < 4; ++fn) {
      float s = ps[fn], s2 = ps2[fn];
      s += __shfl_xor(s, 1);  s2 += __shfl_xor(s2, 1);
      s += __shfl_xor(s, 2);  s2 += __shfl_xor(s2, 2);
      s += __shfl_xor(s, 4);  s2 += __shfl_xor(s2, 4);
      s += __shfl_xor(s, 16); s2 += __shfl_xor(s2, 16);
      s += __shfl_xor(s, 32); s2 += __shfl_xor(s2, 32);
      if ((lane & 55) == 0) {                 // lanes 0 and 8
        int g = wn * 8 + fn * 2 + (ln >> 3);
        atomicAdd(&st2sum[bimg * 64 + g * 2 + 0], s);
        atomicAdd(&st2sum[bimg * 64 + g * 2 + 1], s2);
      }
    }
  } else {
    float* tile = (float*)lds;              // [64][257] f32
    const int pixb = m_base & 4095;
#pragma unroll
    for (int c = 0; c < 4; ++c) {
      __syncthreads();
      if (wn == c) {
#pragma unroll
        for (int fn = 0; fn < 4; ++fn) {
          int nl = fn * 16 + ln;
          int co = c * 64 + nl;
          float dsc = epi[bimg * 256 + co];
          float scb = sc_b[co];
#pragma unroll
          for (int fm = 0; fm < 8; ++fm)
#pragma unroll
            for (int i = 0; i < 4; ++i) {
              int ml = wm * 128 + fm * 16 + (l4 << 2) + i;
              tile[nl * 257 + ml] = acc[fm][fn][i] * dsc + scb;
            }
        }
      }
      __syncthreads();
#pragma unroll 4
      for (int it = 0; it < 32; ++it) {
        int lin = it * 512 + tid;
        int co_l = lin >> 8, ml = lin & 255;
        fout[((size_t)(bimg * 256 + c * 64 + co_l)) * 4096 + pixb + ml] =
            tile[co_l * 257 + ml];
      }
    }
  }
}

// ------------------------------- launch -------------------------------
extern "C" void kernel_launch(void* const* d_in, const int* in_sizes, int n_in,
                              void* d_out, int out_size, void* d_ws, size_t ws_size,
                              hipStream_t stream) {
  const float* x       = (const float*)d_in[0];
  const float* temb    = (const float*)d_in[1];
  const float* style   = (const float*)d_in[2];
  const float* gn1_g   = (const float*)d_in[3];
  const float* gn1_b   = (const float*)d_in[4];
  const float* conv1_w = (const float*)d_in[5];
  const float* conv1_b = (const float*)d_in[6];
  const float* temb_w  = (const float*)d_in[7];
  const float* temb_b  = (const float*)d_in[8];
  const float* gn2_g   = (const float*)d_in[9];
  const float* gn2_b   = (const float*)d_in[10];
  const float* style_w = (const float*)d_in[11];
  const float* style_b = (const float*)d_in[12];
  const float* mod_w   = (const float*)d_in[13];
  const float* sc_w    = (const float*)d_in[14];
  const float* sc_b    = (const float*)d_in[15];
  float* out = (float*)d_out;
  char* ws = (char*)d_ws;

  size_t o = 0;
  auto alloc = [&](size_t bytes) { size_t r = o; o += (bytes + 255) & ~(size_t)255; return r; };
  const size_t act1p_bytes = (size_t)32 * HP * WP * 128 * 2;
  const size_t xh_bytes    = (size_t)32 * 64 * 64 * 128 * 2;
  const size_t h1_bytes    = (size_t)32 * 4096 * 256 * 2;
  const size_t act2p_bytes = (size_t)32 * HP * WP * 256 * 2;
  size_t o_act1p = alloc(act1p_bytes);
  size_t o_xh    = alloc(xh_bytes);
  size_t o_h1    = alloc(h1_bytes);
  size_t o_act2p = alloc(act2p_bytes);
  size_t o_w1T   = alloc((size_t)256 * 1152 * 2);
  size_t o_wmT   = alloc((size_t)256 * 2304 * 2);
  size_t o_scTb  = alloc((size_t)32 * 256 * 128 * 2);
  size_t o_tb2   = alloc(8192 * 4);
  size_t o_mvec  = alloc(8192 * 4);
  size_t o_dvec  = alloc(8192 * 4);
  size_t o_SS    = alloc((size_t)256 * 256 * 4);
  size_t o_st1   = alloc(1024 * 8);
  size_t o_s2sum = alloc(32 * 32 * 2 * 4);
  if (ws_size < o) return;

  u16*    act1p = (u16*)(ws + o_act1p);
  u16*    xh    = (u16*)(ws + o_xh);
  u16*    h1    = (u16*)(ws + o_h1);
  u16*    act2p = (u16*)(ws + o_act2p);
  u16*    w1T   = (u16*)(ws + o_w1T);
  u16*    wmT   = (u16*)(ws + o_wmT);
  u16*    scTb  = (u16*)(ws + o_scTb);
  float*  tb2   = (float*)(ws + o_tb2);
  float*  mvec  = (float*)(ws + o_mvec);
  float*  dvec  = (float*)(ws + o_dvec);
  float*  SS_T  = (float*)(ws + o_SS);
  float2* st1   = (float2*)(ws + o_st1);
  float*  s2sum = (float*)(ws + o_s2sum);

  // zero halo borders + GN2 atomic accumulator
  halo_zero_kernel<128><<<(32 * 260 * 16 + 255) / 256, 256, 0, stream>>>(act1p);
  halo_zero_kernel<256><<<(32 * 260 * 32 + 255) / 256, 256, 0, stream>>>(act2p);
  hipMemsetAsync(s2sum, 0, 32 * 32 * 2 * 4, stream);

  repack_w_kernel<<<1152, 256, 0, stream>>>(conv1_w, w1T, 128, 1152, 256 * 1152, 9, 3);
  repack_w_kernel<<<2304, 256, 0, stream>>>(mod_w, wmT, 256, 2304, 256 * 2304, 9, 3);
  modw_ss_kernel<<<256, 256, 0, stream>>>(mod_w, SS_T);
  temb_proj_kernel<<<32, 256, 0, stream>>>(temb, temb_w, temb_b, conv1_b, tb2);
  style_mvec_kernel<<<32, 256, 0, stream>>>(style, style_w, style_b, mvec);
  demod_kernel<<<32, 256, 0, stream>>>(mvec, SS_T, dvec);
  scale_sc_kernel<<<4096, 256, 0, stream>>>(sc_w, dvec, scTb);
  gn1_stats_kernel<<<1024, 256, 0, stream>>>(x, st1);
  gn1_apply_kernel<<<2048, 256, 0, stream>>>(x, st1, gn1_g, gn1_b, act1p, xh);

  igemm_kernel<0><<<512, 512, 0, stream>>>(act1p, w1T, tb2, nullptr, nullptr,
                                           nullptr, h1, nullptr, s2sum);

  gn2_apply_kernel<<<16384, 256, 0, stream>>>(h1, s2sum, gn2_g, gn2_b, mvec, act2p);

  igemm_kernel<2><<<512, 512, 0, stream>>>(act2p, wmT, dvec, xh, scTb,
                                           sc_b, nullptr, out, nullptr);
}

// Round 13
// 340.674 us; speedup vs baseline: 1.9293x; 1.1053x over previous
//
#include <hip/hip_runtime.h>
#include <cstdint>

typedef unsigned short u16;
typedef unsigned int   u32;

typedef __attribute__((ext_vector_type(8))) short bf16x8;
typedef __attribute__((ext_vector_type(4))) float f32x4;

#define DEV __device__ __forceinline__

static constexpr int HP = 66, WP = 66;   // padded spatial

DEV u16 f2bf(float f) {
  u32 u = __float_as_uint(f);
  u32 r = (u + 0x7fffu + ((u >> 16) & 1u)) >> 16;
  return (u16)r;
}
DEV float bf2f(u16 v) { return __uint_as_float((u32)v << 16); }

DEV void gload_lds16(const void* g, void* s) {
  __builtin_amdgcn_global_load_lds(
      (const __attribute__((address_space(1))) void*)g,
      (__attribute__((address_space(3))) void*)s, 16, 0, 0);
}

// ---- prep mega-kernel: w1T repack | wmT repack | SS_T | halo zeros | s2sum zero ----
// segments by blockIdx.x:
//  [0,1152)        w1T: conv1_w OIHW -> [co][(ky*3+kx)*128+ci] bf16
//  [1152,3456)     wmT: mod_w  OIHW -> [co][(ky*3+kx)*256+ci] bf16
//  [3456,3712)     SS_T[i][o] = sum_k mod_w[o][i][k]^2
//  [3712,4232)     act1p halo zero (C=128)
//  [4232,5272)     act2p halo zero (C=256)
//  [5272]          s2sum zero (2048 floats)
__global__ __launch_bounds__(256) void prep_kernel(const float* __restrict__ conv1_w,
                                                   const float* __restrict__ mod_w,
                                                   u16* __restrict__ w1T,
                                                   u16* __restrict__ wmT,
                                                   float* __restrict__ SS_T,
                                                   u16* __restrict__ act1p,
                                                   u16* __restrict__ act2p,
                                                   float* __restrict__ s2sum) {
  int blk = blockIdx.x, t = threadIdx.x;
  if (blk < 1152) {
    int idx = blk * 256 + t;                       // 256*1152 elems
    int co = idx / 1152, r = idx - co * 1152;
    int s = r >> 7, ci = r & 127;
    int ky = s / 3, kx = s - ky * 3;
    w1T[idx] = f2bf(conv1_w[(co * 128 + ci) * 9 + ky * 3 + kx]);
  } else if (blk < 3456) {
    int idx = (blk - 1152) * 256 + t;              // 256*2304 elems
    int co = idx / 2304, r = idx - co * 2304;
    int s = r >> 8, ci = r & 255;
    int ky = s / 3, kx = s - ky * 3;
    wmT[idx] = f2bf(mod_w[(co * 256 + ci) * 9 + ky * 3 + kx]);
  } else if (blk < 3712) {
    int o = blk - 3456, i = t;
    const float* p = mod_w + (size_t)(o * 256 + i) * 9;
    float s = 0.f;
#pragma unroll
    for (int k = 0; k < 9; ++k) s += p[k] * p[k];
    SS_T[i * 256 + o] = s;
  } else if (blk < 5272) {
    bool big = blk >= 4232;
    int idx = (big ? (blk - 4232) : (blk - 3712)) * 256 + t;
    const int GR = big ? 32 : 16;
    int g = idx % GR;
    int p = (idx / GR) % 260;
    int b = idx / (GR * 260);
    int y, x;
    if (p < 66)       { y = 0;       x = p; }
    else if (p < 132) { y = 65;      x = p - 66; }
    else if (p < 196) { y = p - 131; x = 0; }
    else              { y = p - 195; x = 65; }
    uint4 z; z.x = 0; z.y = 0; z.z = 0; z.w = 0;
    u16* buf = big ? act2p : act1p;
    int C = big ? 256 : 128;
    *(uint4*)(buf + (((size_t)b * HP + y) * WP + x) * C + g * 8) = z;
  } else {
    *(float2*)(s2sum + t * 8)     = make_float2(0.f, 0.f);
    *(float2*)(s2sum + t * 8 + 2) = make_float2(0.f, 0.f);
    *(float2*)(s2sum + t * 8 + 4) = make_float2(0.f, 0.f);
    *(float2*)(s2sum + t * 8 + 6) = make_float2(0.f, 0.f);
  }
}

// ---- temb projection (blocks 0..31) + style mvec (blocks 32..63) -------------------
__global__ __launch_bounds__(256) void temb_style_kernel(const float* __restrict__ temb,
                                                         const float* __restrict__ temb_w,
                                                         const float* __restrict__ temb_b,
                                                         const float* __restrict__ conv1_b,
                                                         const float* __restrict__ style,
                                                         const float* __restrict__ style_w,
                                                         const float* __restrict__ style_b,
                                                         float* __restrict__ tb2,
                                                         float* __restrict__ mvec) {
  __shared__ float sw[512];
  int blk = blockIdx.x, t = threadIdx.x;
  if (blk < 32) {
    int b = blk;
    for (int k = t; k < 512; k += 256) {
      float v = temb[b * 512 + k];
      sw[k] = v / (1.f + __expf(-v));
    }
    __syncthreads();
    const float4* wr = (const float4*)(temb_w + t * 512);
    float acc = 0.f;
    for (int k = 0; k < 128; ++k) {
      float4 w4 = wr[k];
      acc += w4.x * sw[k*4] + w4.y * sw[k*4+1] + w4.z * sw[k*4+2] + w4.w * sw[k*4+3];
    }
    tb2[b * 256 + t] = acc + temb_b[t] + conv1_b[t];
  } else {
    int b = blk - 32;
    for (int k = t; k < 512; k += 256) sw[k] = style[b * 512 + k];
    __syncthreads();
    const float4* wr = (const float4*)(style_w + t * 512);
    float acc = 0.f;
    for (int k = 0; k < 128; ++k) {
      float4 w4 = wr[k];
      acc += w4.x * sw[k*4] + w4.y * sw[k*4+1] + w4.z * sw[k*4+2] + w4.w * sw[k*4+3];
    }
    mvec[b * 256 + t] = acc + style_b[t] + 1.f;
  }
}

// ---------------- dvec[b][o] = rsqrt(sum_i mvec[b][i]^2 * SS_T[i][o] + eps) ---------
__global__ __launch_bounds__(256) void demod_kernel(const float* __restrict__ mvec,
                                                    const float* __restrict__ SS_T,
                                                    float* __restrict__ dvec) {
  __shared__ float m2[256];
  int b = blockIdx.x, t = threadIdx.x;
  float mv = mvec[b * 256 + t];
  m2[t] = mv * mv;
  __syncthreads();
  float acc = 0.f;
  for (int i = 0; i < 256; ++i) acc += m2[i] * SS_T[i * 256 + t];
  dvec[b * 256 + t] = rsqrtf(acc + 1e-8f);
}

// ---------------- scTb[b][co][ci] = sc_w[co][ci] / dvec[b][co]  (bf16) --------------
__global__ __launch_bounds__(256) void scale_sc_kernel(const float* __restrict__ sc_w,
                                                       const float* __restrict__ dvec,
                                                       u16* __restrict__ scTb) {
  int idx = blockIdx.x * 256 + threadIdx.x;   // 32*256*128 total
  int ci = idx & 127;
  int co = (idx >> 7) & 255;
  int b  = idx >> 15;
  scTb[idx] = f2bf(sc_w[co * 128 + ci] / dvec[b * 256 + co]);
}

// ---------------- GN1 stats ----------------
__global__ __launch_bounds__(256) void gn1_stats_kernel(const float* __restrict__ x,
                                                        float2* __restrict__ st1) {
  int bg = blockIdx.x;
  const float4* p = (const float4*)(x + (size_t)bg * 16384);
  float s = 0.f, s2 = 0.f;
  for (int i = threadIdx.x; i < 4096; i += 256) {
    float4 v = p[i];
    s  += v.x + v.y + v.z + v.w;
    s2 += v.x*v.x + v.y*v.y + v.z*v.z + v.w*v.w;
  }
  for (int d = 32; d; d >>= 1) { s += __shfl_down(s, d); s2 += __shfl_down(s2, d); }
  __shared__ float red[2][4];
  if ((threadIdx.x & 63) == 0) { red[0][threadIdx.x >> 6] = s; red[1][threadIdx.x >> 6] = s2; }
  __syncthreads();
  if (threadIdx.x == 0) {
    s  = red[0][0] + red[0][1] + red[0][2] + red[0][3];
    s2 = red[1][0] + red[1][1] + red[1][2] + red[1][3];
    float mean = s / 16384.f;
    float var  = s2 / 16384.f - mean * mean;
    st1[bg] = make_float2(mean, rsqrtf(var + 1e-5f));
  }
}

// -------- GN1 apply + swish -> act1p; x -> xh. Vectorized uint4 (8-ch) stores. ------
// LDS xs[x][c] (pad to 129): stage-1 writes conflict-free (bank = lane%32);
// stage-2 scalar reads are 2-way (free). 4 store passes, 16B/lane, coalesced.
__global__ __launch_bounds__(256) void gn1_apply_kernel(const float* __restrict__ x,
                                                        const float2* __restrict__ st1,
                                                        const float* __restrict__ g1,
                                                        const float* __restrict__ b1,
                                                        u16* __restrict__ act1p,
                                                        u16* __restrict__ xh) {
  __shared__ float xs[64][129];
  int blk = blockIdx.x;
  int b = blk >> 6, y = blk & 63;
  int t = threadIdx.x;
#pragma unroll 8
  for (int pass = 0; pass < 32; ++pass) {
    int c = pass * 4 + (t >> 6);
    xs[t & 63][c] = x[(((size_t)b * 128 + c) * 64 + y) * 64 + (t & 63)];
  }
  __syncthreads();
  const int cg = t & 15, c0 = cg * 8;
  float2 msA = st1[b * 32 + cg * 2];
  float2 msB = st1[b * 32 + cg * 2 + 1];
  float g1r[8], b1r[8];
#pragma unroll
  for (int e = 0; e < 8; ++e) { g1r[e] = g1[c0 + e]; b1r[e] = b1[c0 + e]; }
#pragma unroll
  for (int p = 0; p < 4; ++p) {
    int xi = p * 16 + (t >> 4);
    u16 outA[8], outX[8];
#pragma unroll
    for (int e = 0; e < 8; ++e) {
      float v = xs[xi][c0 + e];
      float2 ms = (e < 4) ? msA : msB;
      float vn = (v - ms.x) * ms.y * g1r[e] + b1r[e];
      float sw = vn / (1.f + __expf(-vn));
      outA[e] = f2bf(sw);
      outX[e] = f2bf(v);
    }
    *(uint4*)(act1p + (((size_t)b * HP + (y + 1)) * WP + (xi + 1)) * 128 + c0) =
        *(const uint4*)outA;
    *(uint4*)(xh + (((size_t)b * 64 + y) * 64 + xi) * 128 + c0) = *(const uint4*)outX;
  }
}

// -- GN2 apply (stats inline from totals) + swish + in-channel mod: h1 -> act2p ------
__global__ __launch_bounds__(256) void gn2_apply_kernel(const u16* __restrict__ h1,
                                                        const float* __restrict__ st2sum,
                                                        const float* __restrict__ g2,
                                                        const float* __restrict__ b2,
                                                        const float* __restrict__ mvec,
                                                        u16* __restrict__ act2p) {
  int idx = blockIdx.x * 256 + threadIdx.x;  // granule id
  int gpix = idx >> 5;
  int gi = idx & 31;
  int c0 = gi * 8;
  int b = gpix >> 12, y = (gpix >> 6) & 63, x = gpix & 63;
  uint4 raw = *(const uint4*)(h1 + (size_t)gpix * 256 + c0);
  const u16* rs = (const u16*)&raw;
  float s  = st2sum[b * 64 + gi * 2];
  float s2 = st2sum[b * 64 + gi * 2 + 1];
  float mean = s / 32768.f;
  float rstd = rsqrtf(s2 / 32768.f - mean * mean + 1e-5f);
  const float* mv = mvec + b * 256 + c0;
  u16 outp[8];
#pragma unroll
  for (int e = 0; e < 8; ++e) {
    float v  = bf2f(rs[e]);
    float vn = (v - mean) * rstd * g2[c0 + e] + b2[c0 + e];
    float sw = vn / (1.f + __expf(-vn));
    outp[e] = f2bf(sw * mv[e]);
  }
  *(uint4*)(act2p + (((size_t)b * HP + (y + 1)) * WP + (x + 1)) * 256 + c0) = *(const uint4*)outp;
}

// ---------- implicit-GEMM conv: 256x256 tile, 8 waves, BK=64, 4-phase schedule ------
// EXACT round-7 proven schedule (159us MODE2, MfmaUtil 45.4%, twice reproduced):
// per phase = stage next half -> vmcnt(6) -> barrier -> ds_read frags -> MFMA.
// MODE 0: conv1 -> h1 bf16 NHWC + fused GN2 partial stats (atomics).
// MODE 2: modconv + fused 1x1 shortcut -> d_out NCHW fp32 = acc*dvec + sc_b.
template <int MODE>
__global__ __launch_bounds__(512, 2) void igemm_kernel(const u16* __restrict__ act,
                                                       const u16* __restrict__ wT,
                                                       const float* __restrict__ epi,
                                                       const u16* __restrict__ xh,
                                                       const u16* __restrict__ scTb,
                                                       const float* __restrict__ sc_b,
                                                       u16* __restrict__ h1out,
                                                       float* __restrict__ fout,
                                                       float* __restrict__ st2sum) {
  constexpr int CIN    = (MODE == 0) ? 128 : 256;
  constexpr int NSUB   = CIN / 64;
  constexpr int KW     = CIN * 9;
  constexpr int NKMAIN = KW / 64;                 // 18 / 36
  constexpr int NKT    = (MODE == 2) ? NKMAIN + 2 : NKMAIN;

  __shared__ __align__(16) unsigned char lds[131072];
  const int tid  = threadIdx.x;
  const int wave = tid >> 6, lane = tid & 63;
  const int wm = wave >> 2, wn = wave & 3;        // 2 x 4 waves
  const int m_base = blockIdx.x * 256;
  const int bimg = m_base >> 12;
  const int ln = lane & 15, l4 = lane >> 4;

  // staging lane constants
  const int srow = lane >> 3;                     // 0..7
  const int glog = (lane & 7) ^ srow;             // pre-swizzled source granule

  u32 pixA[2][2], pixX[2][2], rowB[2][2], rowS[2][2];
#pragma unroll
  for (int j = 0; j < 2; ++j)
#pragma unroll
    for (int h = 0; h < 2; ++h) {
      int mlocal = (wave & 3) * 16 + j * 8 + srow + h * 64 + (wave >> 2) * 128;
      int m = m_base + mlocal;
      int y = (m >> 6) & 63, x = m & 63;
      pixA[j][h] = (u32)((bimg * HP + y) * WP + x) * CIN + glog * 8;
      if (MODE == 2) pixX[j][h] = (u32)m * 128 + glog * 8;
      int co = (wave >> 1) * 64 + h * 32 + (wave & 1) * 16 + j * 8 + srow;
      rowB[j][h] = (u32)co * KW + glog * 8;
      if (MODE == 2) rowS[j][h] = (u32)(bimg * 256 + co) * 128 + glog * 8;
    }

  f32x4 acc[8][4];
#pragma unroll
  for (int i = 0; i < 8; ++i)
#pragma unroll
    for (int j = 0; j < 4; ++j) acc[i][j] = (f32x4){0.f, 0.f, 0.f, 0.f};

  auto stageA = [&](int kt, int h, int buf) {
    unsigned char* dst = lds + buf * 65536 + h * 16384 + wave * 2048;
    if (MODE == 2 && kt >= NKMAIN) {
      u32 ko = (u32)(kt - NKMAIN) * 64;
      gload_lds16(xh + pixX[0][h] + ko, dst);
      gload_lds16(xh + pixX[1][h] + ko, dst + 1024);
    } else {
      int tap = kt / NSUB;
      int kin = (kt - tap * NSUB) * 64;
      int ky = tap / 3, kx = tap - ky * 3;
      u32 ko = (u32)((ky * WP + kx) * CIN + kin);
      gload_lds16(act + pixA[0][h] + ko, dst);
      gload_lds16(act + pixA[1][h] + ko, dst + 1024);
    }
  };
  auto stageB = [&](int kt, int g, int buf) {
    unsigned char* dst = lds + buf * 65536 + 32768 + g * 16384 + wave * 2048;
    if (MODE == 2 && kt >= NKMAIN) {
      u32 ko = (u32)(kt - NKMAIN) * 64;
      gload_lds16(scTb + rowS[0][g] + ko, dst);
      gload_lds16(scTb + rowS[1][g] + ko, dst + 1024);
    } else {
      u32 ko = (u32)kt * 64;
      gload_lds16(wT + rowB[0][g] + ko, dst);
      gload_lds16(wT + rowB[1][g] + ko, dst + 1024);
    }
  };

  bf16x8 af[8], bf[4];
  auto ldA = [&](int h, int buf) {
    const unsigned char* As = lds + buf * 65536;
#pragma unroll
    for (int f = 0; f < 4; ++f)
#pragma unroll
      for (int kk = 0; kk < 2; ++kk) {
        int lr = h * 128 + wm * 64 + f * 16 + ln;
        int gr = (kk * 4 + l4) ^ (lr & 7);
        af[f * 2 + kk] = *(const bf16x8*)(As + lr * 128 + gr * 16);
      }
  };
  auto ldB = [&](int g, int buf) {
    const unsigned char* Bs = lds + buf * 65536 + 32768;
#pragma unroll
    for (int f1 = 0; f1 < 2; ++f1)
#pragma unroll
      for (int kk = 0; kk < 2; ++kk) {
        int lr = g * 128 + wn * 32 + f1 * 16 + ln;
        int gr = (kk * 4 + l4) ^ (lr & 7);
        bf[f1 * 2 + kk] = *(const bf16x8*)(Bs + lr * 128 + gr * 16);
      }
  };
  auto mmac = [&](int h, int g) {
    __builtin_amdgcn_s_setprio(1);
#pragma unroll
    for (int f = 0; f < 4; ++f)
#pragma unroll
      for (int f1 = 0; f1 < 2; ++f1)
#pragma unroll
        for (int kk = 0; kk < 2; ++kk)
          acc[h * 4 + f][g * 2 + f1] = __builtin_amdgcn_mfma_f32_16x16x32_bf16(
              af[f * 2 + kk], bf[f1 * 2 + kk], acc[h * 4 + f][g * 2 + f1], 0, 0, 0);
    __builtin_amdgcn_s_setprio(0);
  };

#define PHASE_BAR() do { __builtin_amdgcn_sched_barrier(0); \
    __builtin_amdgcn_s_barrier(); __builtin_amdgcn_sched_barrier(0); } while (0)

  // prologue: tile 0 -> buf0, in consumption order Ah0, Bg0, Bg1, Ah1
  stageA(0, 0, 0); stageB(0, 0, 0); stageB(0, 1, 0); stageA(0, 1, 0);

#pragma unroll 2
  for (int kt = 0; kt < NKT - 1; ++kt) {
    const int cur = kt & 1, nxt = cur ^ 1;
    // ph0: (h0,g0)
    stageA(kt + 1, 0, nxt);
    asm volatile("s_waitcnt vmcnt(6)" ::: "memory");
    PHASE_BAR();
    ldB(0, cur); ldA(0, cur);
    mmac(0, 0);
    // ph1: (h0,g1)
    stageB(kt + 1, 0, nxt);
    asm volatile("s_waitcnt vmcnt(6)" ::: "memory");
    PHASE_BAR();
    ldB(1, cur);
    mmac(0, 1);
    // ph2: (h1,g1)
    stageB(kt + 1, 1, nxt);
    asm volatile("s_waitcnt vmcnt(6)" ::: "memory");
    PHASE_BAR();
    ldA(1, cur);
    mmac(1, 1);
    // ph3: (h1,g0)
    stageA(kt + 1, 1, nxt);
    PHASE_BAR();
    ldB(0, cur);
    mmac(1, 0);
  }
  {  // last tile (no staging): drain progressively
    const int cur = (NKT - 1) & 1;
    asm volatile("s_waitcnt vmcnt(4)" ::: "memory");
    PHASE_BAR();
    ldB(0, cur); ldA(0, cur); mmac(0, 0);
    asm volatile("s_waitcnt vmcnt(2)" ::: "memory");
    PHASE_BAR();
    ldB(1, cur); mmac(0, 1);
    asm volatile("s_waitcnt vmcnt(0)" ::: "memory");
    PHASE_BAR();
    ldA(1, cur); mmac(1, 1);
    PHASE_BAR();
    ldB(0, cur); mmac(1, 0);
  }
#undef PHASE_BAR

  if (MODE == 0) {
    const float* tbrow = epi + bimg * 256;
    float ps[4], ps2[4];
#pragma unroll
    for (int fn = 0; fn < 4; ++fn) { ps[fn] = 0.f; ps2[fn] = 0.f; }
#pragma unroll
    for (int fm = 0; fm < 8; ++fm)
#pragma unroll
      for (int fn = 0; fn < 4; ++fn) {
        int co = wn * 64 + fn * 16 + ln;
        float add = tbrow[co];
#pragma unroll
        for (int i = 0; i < 4; ++i) {
          int m = m_base + wm * 128 + fm * 16 + (l4 << 2) + i;
          float v = acc[fm][fn][i] + add;
          h1out[(size_t)m * 256 + co] = f2bf(v);
          ps[fn] += v; ps2[fn] += v * v;
        }
      }
    // fused GN2 partial stats (channel-group g = co>>3)
#pragma unroll
    for (int fn = 0; fn < 4; ++fn) {
      float s = ps[fn], s2 = ps2[fn];
      s += __shfl_xor(s, 1);  s2 += __shfl_xor(s2, 1);
      s += __shfl_xor(s, 2);  s2 += __shfl_xor(s2, 2);
      s += __shfl_xor(s, 4);  s2 += __shfl_xor(s2, 4);
      s += __shfl_xor(s, 16); s2 += __shfl_xor(s2, 16);
      s += __shfl_xor(s, 32); s2 += __shfl_xor(s2, 32);
      if ((lane & 55) == 0) {                 // lanes 0 and 8
        int g = wn * 8 + fn * 2 + (ln >> 3);
        atomicAdd(&st2sum[bimg * 64 + g * 2 + 0], s);
        atomicAdd(&st2sum[bimg * 64 + g * 2 + 1], s2);
      }
    }
  } else {
    float* tile = (float*)lds;              // [64][257] f32
    const int pixb = m_base & 4095;
#pragma unroll
    for (int c = 0; c < 4; ++c) {
      __syncthreads();
      if (wn == c) {
#pragma unroll
        for (int fn = 0; fn < 4; ++fn) {
          int nl = fn * 16 + ln;
          int co = c * 64 + nl;
          float dsc = epi[bimg * 256 + co];
          float scb = sc_b[co];
#pragma unroll
          for (int fm = 0; fm < 8; ++fm)
#pragma unroll
            for (int i = 0; i < 4; ++i) {
              int ml = wm * 128 + fm * 16 + (l4 << 2) + i;
              tile[nl * 257 + ml] = acc[fm][fn][i] * dsc + scb;
            }
        }
      }
      __syncthreads();
#pragma unroll 4
      for (int it = 0; it < 32; ++it) {
        int lin = it * 512 + tid;
        int co_l = lin >> 8, ml = lin & 255;
        fout[((size_t)(bimg * 256 + c * 64 + co_l)) * 4096 + pixb + ml] =
            tile[co_l * 257 + ml];
      }
    }
  }
}

// ------------------------------- launch -------------------------------
extern "C" void kernel_launch(void* const* d_in, const int* in_sizes, int n_in,
                              void* d_out, int out_size, void* d_ws, size_t ws_size,
                              hipStream_t stream) {
  const float* x       = (const float*)d_in[0];
  const float* temb    = (const float*)d_in[1];
  const float* style   = (const float*)d_in[2];
  const float* gn1_g   = (const float*)d_in[3];
  const float* gn1_b   = (const float*)d_in[4];
  const float* conv1_w = (const float*)d_in[5];
  const float* conv1_b = (const float*)d_in[6];
  const float* temb_w  = (const float*)d_in[7];
  const float* temb_b  = (const float*)d_in[8];
  const float* gn2_g   = (const float*)d_in[9];
  const float* gn2_b   = (const float*)d_in[10];
  const float* style_w = (const float*)d_in[11];
  const float* style_b = (const float*)d_in[12];
  const float* mod_w   = (const float*)d_in[13];
  const float* sc_w    = (const float*)d_in[14];
  const float* sc_b    = (const float*)d_in[15];
  float* out = (float*)d_out;
  char* ws = (char*)d_ws;

  size_t o = 0;
  auto alloc = [&](size_t bytes) { size_t r = o; o += (bytes + 255) & ~(size_t)255; return r; };
  const size_t act1p_bytes = (size_t)32 * HP * WP * 128 * 2;
  const size_t xh_bytes    = (size_t)32 * 64 * 64 * 128 * 2;
  const size_t h1_bytes    = (size_t)32 * 4096 * 256 * 2;
  const size_t act2p_bytes = (size_t)32 * HP * WP * 256 * 2;
  size_t o_act1p = alloc(act1p_bytes);
  size_t o_xh    = alloc(xh_bytes);
  size_t o_h1    = alloc(h1_bytes);
  size_t o_act2p = alloc(act2p_bytes);
  size_t o_w1T   = alloc((size_t)256 * 1152 * 2);
  size_t o_wmT   = alloc((size_t)256 * 2304 * 2);
  size_t o_scTb  = alloc((size_t)32 * 256 * 128 * 2);
  size_t o_tb2   = alloc(8192 * 4);
  size_t o_mvec  = alloc(8192 * 4);
  size_t o_dvec  = alloc(8192 * 4);
  size_t o_SS    = alloc((size_t)256 * 256 * 4);
  size_t o_st1   = alloc(1024 * 8);
  size_t o_s2sum = alloc(32 * 32 * 2 * 4);
  if (ws_size < o) return;

  u16*    act1p = (u16*)(ws + o_act1p);
  u16*    xh    = (u16*)(ws + o_xh);
  u16*    h1    = (u16*)(ws + o_h1);
  u16*    act2p = (u16*)(ws + o_act2p);
  u16*    w1T   = (u16*)(ws + o_w1T);
  u16*    wmT   = (u16*)(ws + o_wmT);
  u16*    scTb  = (u16*)(ws + o_scTb);
  float*  tb2   = (float*)(ws + o_tb2);
  float*  mvec  = (float*)(ws + o_mvec);
  float*  dvec  = (float*)(ws + o_dvec);
  float*  SS_T  = (float*)(ws + o_SS);
  float2* st1   = (float2*)(ws + o_st1);
  float*  s2sum = (float*)(ws + o_s2sum);

  prep_kernel<<<5273, 256, 0, stream>>>(conv1_w, mod_w, w1T, wmT, SS_T,
                                        act1p, act2p, s2sum);
  temb_style_kernel<<<64, 256, 0, stream>>>(temb, temb_w, temb_b, conv1_b,
                                            style, style_w, style_b, tb2, mvec);
  gn1_stats_kernel<<<1024, 256, 0, stream>>>(x, st1);
  gn1_apply_kernel<<<2048, 256, 0, stream>>>(x, st1, gn1_g, gn1_b, act1p, xh);
  demod_kernel<<<32, 256, 0, stream>>>(mvec, SS_T, dvec);
  scale_sc_kernel<<<4096, 256, 0, stream>>>(sc_w, dvec, scTb);

  igemm_kernel<0><<<512, 512, 0, stream>>>(act1p, w1T, tb2, nullptr, nullptr,
                                           nullptr, h1, nullptr, s2sum);

  gn2_apply_kernel<<<16384, 256, 0, stream>>>(h1, s2sum, gn2_g, gn2_b, mvec, act2p);

  igemm_kernel<2><<<512, 512, 0, stream>>>(act2p, wmT, dvec, xh, scTb,
                                           sc_b, nullptr, out, nullptr);
}